// Round 11
// baseline (1914.832 us; speedup 1.0000x reference)
//
#include <hip/hip_runtime.h>
#include <hip/hip_fp8.h>
#include <math.h>

#define NN 10000
#define NE 320000
#define PI_F 3.14159265358979323846f
#define NCHK 8
#define MAXCH 1350   // >= sum_t ceil(cnt_t/NCHK) worst case = NN/8 + 100

typedef __attribute__((ext_vector_type(8))) short short8x;
typedef __attribute__((ext_vector_type(4))) float float4x;

#if defined(__has_builtin)
#if __has_builtin(__builtin_amdgcn_cvt_pk_fp8_f32) && __has_builtin(__builtin_amdgcn_cvt_f32_fp8)
#define HW_FP8 1
#endif
#endif

__device__ __forceinline__ unsigned short f2b(float f) {
    unsigned b = __float_as_uint(f);
    return (unsigned short)((b + 0x7FFFu + ((b >> 16) & 1u)) >> 16);
}
__device__ __forceinline__ float b2f(unsigned short u) {
    return __uint_as_float(((unsigned)u) << 16);
}
__device__ __forceinline__ float silu(float x) {
    return x / (1.f + __expf(-x));
}
__device__ __forceinline__ unsigned char f2e4(float f) {
#ifdef HW_FP8
    int r = __builtin_amdgcn_cvt_pk_fp8_f32(f, f, 0, false);
    return (unsigned char)(r & 0xff);
#else
    __hip_fp8_e4m3 q(f);
    return (unsigned char)q.__x;
#endif
}
__device__ __forceinline__ float e42f(unsigned char v) {
#ifdef HW_FP8
    return __builtin_amdgcn_cvt_f32_fp8((int)v, 0);
#else
    __hip_fp8_e4m3 q;
    q.__x = (__hip_fp8_storage_t)v;
    return (float)q;
#endif
}
// byte-select decode: builtin requires IMMEDIATE sel -> switch with literal cases
__device__ __forceinline__ float e4sel(unsigned word, int sel) {
#ifdef HW_FP8
    switch (sel & 3) {
        case 0:  return __builtin_amdgcn_cvt_f32_fp8((int)word, 0);
        case 1:  return __builtin_amdgcn_cvt_f32_fp8((int)word, 1);
        case 2:  return __builtin_amdgcn_cvt_f32_fp8((int)word, 2);
        default: return __builtin_amdgcn_cvt_f32_fp8((int)word, 3);
    }
#else
    return e42f((unsigned char)((word >> (8*(sel & 3))) & 0xffu));
#endif
}
__device__ __forceinline__ unsigned pk4(float a, float b, float c, float d) {
#ifdef HW_FP8
    unsigned w = (unsigned)__builtin_amdgcn_cvt_pk_fp8_f32(a, b, 0, false);
    w = (unsigned)__builtin_amdgcn_cvt_pk_fp8_f32(c, d, (int)w, true);
    return w;
#else
    return (unsigned)f2e4(a) | ((unsigned)f2e4(b) << 8) |
           ((unsigned)f2e4(c) << 16) | ((unsigned)f2e4(d) << 24);
#endif
}

// ---------------- K = Newton-Schulz semi-unitary (16x2) ----------------
__global__ void k_newton_kernel(const float* __restrict__ PU, float* __restrict__ Kout)
{
    if (threadIdx.x != 0 || blockIdx.x != 0) return;
    float K[32];
    float nrm = 0.f;
    for (int i = 0; i < 32; ++i) { K[i] = PU[i]; nrm += K[i]*K[i]; }
    float inv = 1.0f / sqrtf(nrm);
    for (int i = 0; i < 32; ++i) K[i] *= inv;
    for (int it = 0; it < 10; ++it) {
        float m00 = 0.f, m01 = 0.f, m11 = 0.f;
        for (int u = 0; u < 16; ++u) {
            float a = K[2*u], b = K[2*u+1];
            m00 += a*a; m01 += a*b; m11 += b*b;
        }
        for (int u = 0; u < 16; ++u) {
            float a = K[2*u], b = K[2*u+1];
            K[2*u]   = 1.5f*a - 0.5f*(a*m00 + b*m01);
            K[2*u+1] = 1.5f*b - 0.5f*(a*m01 + b*m11);
        }
    }
    for (int i = 0; i < 32; ++i) Kout[i] = K[i];
}

// ---------------- merged init: x_pad + yv init + zero ys0/ys1/fsb + zero midb ----------------
__global__ __launch_bounds__(256) void init_all_kernel(
    const float* __restrict__ x, const float* __restrict__ K,
    float* __restrict__ xp, float* __restrict__ yv0, float* __restrict__ yv1,
    float* __restrict__ ys0, float* __restrict__ ys1, float* __restrict__ fsb,
    float* __restrict__ midb)
{
    int tid = blockIdx.x*256 + threadIdx.x;
    if (tid < NN*8) {
        int n = tid >> 3, c = tid & 7;
        xp[tid] = (c < 6) ? x[n*6 + c] : 0.f;
        return;
    }
    int t2 = tid - NN*8;
    if (t2 < NN*48) {
        int n = t2/48, j = t2%48, u = j/3, m = j%3;
        float v = K[2*u]*x[n*6+m] + K[2*u+1]*x[n*6+3+m];
        yv0[t2] = v; yv1[t2] = v;
        return;
    }
    t2 -= NN*48;
    if (t2 < NN*64) { ys0[t2] = 0.f; ys1[t2] = 0.f; fsb[t2] = 0.f; return; }
    t2 -= NN*64;
    if (t2 < NN*256) midb[t2] = 0.f;
}

// ---------------- layer-0 fvv init (fs0 = 0 since ys0 = 0) ----------------
__global__ void init_fvv_kernel(const float* __restrict__ yv, const int* __restrict__ types,
                                const float* __restrict__ lin1vT0, float* __restrict__ fvv)
{
    int tid = blockIdx.x*blockDim.x + threadIdx.x;
    if (tid >= NN*48) return;
    int n = tid/48, j = tid%48, o = j/3, m = j%3;
    int t = types[n];
    const float* W = lin1vT0 + (size_t)t*256;
    float acc = 0.f;
    #pragma unroll
    for (int i = 0; i < 16; ++i) acc += yv[n*48 + i*3 + m]*W[i*16 + o];
    fvv[tid] = acc;
}

// ---------------- per-type effective weights (device body) ----------------
__device__ __forceinline__ void be_body(const float* __restrict__ W, const float* __restrict__ emb,
                                        float* __restrict__ out, int id, int O, int I, float scale)
{
    int o = id % O; int r = id / O;
    int i = r % I; r /= I;
    int t = r % 100; int l = r / 100;
    const float* w  = W + (((size_t)l*O + o)*I + i)*32;
    const float* em = emb + (size_t)t*32;
    float acc = 0.f;
    #pragma unroll
    for (int e = 0; e < 32; ++e) acc += w[e]*em[e];
    out[id] = acc*scale;
}

// ---------------- merged weight prep ----------------
#define PREP_TOTAL (2048000 + 1638400 + 512000 + 512000 + 102400 + 102400 + 49152 + 16384 + 16384 + 8192 + 1024)
__global__ __launch_bounds__(256) void prep_kernel(
    const float* __restrict__ lin1_Ws, const float* __restrict__ lin1_Wv,
    const float* __restrict__ sc_Ws,   const float* __restrict__ sc_Wv,
    const float* __restrict__ lin2_Ws, const float* __restrict__ lin2_Wv,
    const float* __restrict__ si_Ws,   const float* __restrict__ si_Wv,
    const float* __restrict__ fc_W1,   const float* __restrict__ fc_W2,
    const float* __restrict__ fc_W3,   const float* __restrict__ emb,
    float* __restrict__ lin1sT, float* __restrict__ lin1vT,
    float* __restrict__ scsT,   float* __restrict__ scvT,
    float* __restrict__ lin2sT, float* __restrict__ lin2vT,
    float* __restrict__ siWsT,  float* __restrict__ siWvT,
    unsigned short* __restrict__ w1bp, unsigned short* __restrict__ w2bp,
    unsigned short* __restrict__ w3bf)
{
    const float s2048 = 0.022097086912079608f;   // 1/sqrt(2048)
    const float s512  = 0.044194173824159216f;   // 1/sqrt(512)
    const float s2560 = 0.019764235376052372f;   // 1/sqrt(2560)
    int tid = blockIdx.x*256 + threadIdx.x;
    if (tid < 2048000) { be_body(sc_Ws,   emb, scsT,   tid, 80, 64, s2048); return; }
    tid -= 2048000;
    if (tid < 1638400) { be_body(lin1_Ws, emb, lin1sT, tid, 64, 64, s2048); return; }
    tid -= 1638400;
    if (tid < 512000)  { be_body(lin2_Ws, emb, lin2sT, tid, 80, 16, s512);  return; }
    tid -= 512000;
    if (tid < 512000)  { be_body(lin2_Wv, emb, lin2vT, tid, 16, 80, s2560); return; }
    tid -= 512000;
    if (tid < 102400)  { be_body(lin1_Wv, emb, lin1vT, tid, 16, 16, s512);  return; }
    tid -= 102400;
    if (tid < 102400)  { be_body(sc_Wv,   emb, scvT,   tid, 16, 16, s512);  return; }
    tid -= 102400;
    if (tid < 49152) {  // w3bf = bf16(transpose(fc_W3)): [l][n=192][k=64]
        int o = tid % 64; int r = tid / 64; int i = r % 192; int l = r / 192;
        w3bf[tid] = f2b(fc_W3[((size_t)l*64 + o)*192 + i]);
        return;
    }
    tid -= 49152;
    if (tid < 16384) {  // siWsT = 0.125 * transpose(si_Ws)
        int o = tid % 64; int r = tid / 64; int i = r % 64; int l = r / 64;
        siWsT[tid] = si_Ws[((size_t)l*64 + o)*64 + i]*0.125f;
        return;
    }
    tid -= 16384;
    if (tid < 16384) {  // w2bp: pack fc_W2 K=64,N=64,KP=64
        int kk = tid % 64; int r = tid / 64; int n = r % 64; int l = r / 64;
        w2bp[tid] = f2b(fc_W2[((size_t)l*64 + kk)*64 + n]);
        return;
    }
    tid -= 16384;
    if (tid < 8192) {   // w1bp: pack fc_W1 K=16,N=64,KP=32 (zero-pad)
        int kk = tid % 32; int r = tid / 32; int n = r % 64; int l = r / 64;
        float v = (kk < 16) ? fc_W1[((size_t)l*16 + kk)*64 + n] : 0.f;
        w1bp[tid] = f2b(v);
        return;
    }
    tid -= 8192;
    if (tid < 1024) {   // siWvT = 0.25 * transpose(si_Wv)
        int o = tid % 16; int r = tid / 16; int i = r % 16; int l = r / 16;
        siWvT[tid] = si_Wv[((size_t)l*16 + o)*16 + i]*0.25f;
    }
}

// ---------------- counting sort of edges by dst ----------------
__global__ void hist_kernel(const int* __restrict__ dst, int* __restrict__ deg)
{
    int e = blockIdx.x*256 + threadIdx.x;
    if (e < NE) atomicAdd(&deg[dst[e]], 1);
}

__global__ __launch_bounds__(256) void scan_kernel(const int* __restrict__ deg,
                                                   int* __restrict__ segoff,
                                                   int* __restrict__ cursor)
{
    __shared__ int part[256];
    int tid = threadIdx.x;
    int base = tid*40;
    int s = 0;
    for (int i = 0; i < 40; ++i) { int idx = base+i; if (idx < NN) s += deg[idx]; }
    part[tid] = s;
    __syncthreads();
    for (int o = 1; o < 256; o <<= 1) {
        int v = (tid >= o) ? part[tid-o] : 0;
        __syncthreads();
        part[tid] += v;
        __syncthreads();
    }
    int excl = part[tid] - s;
    for (int i = 0; i < 40; ++i) {
        int idx = base+i;
        if (idx < NN) { segoff[idx] = excl; cursor[idx] = excl; excl += deg[idx]; }
        else if (idx == NN) { segoff[NN] = excl; }
    }
}

__global__ void scatter_kernel(const int* __restrict__ src, const int* __restrict__ dst,
                               int* __restrict__ cursor,
                               int* __restrict__ srcs, int* __restrict__ dsts)
{
    int e = blockIdx.x*256 + threadIdx.x;
    if (e >= NE) return;
    int d = dst[e];
    int p = atomicAdd(&cursor[d], 1);
    srcs[p] = src[e]; dsts[p] = d;
}

// ---------------- counting sort of nodes by type + chunk table ----------------
__global__ void thist_kernel(const int* __restrict__ types, int* __restrict__ tdeg)
{
    int n = blockIdx.x*256 + threadIdx.x;
    if (n < NN) atomicAdd(&tdeg[types[n]], 1);
}

__global__ __launch_bounds__(128) void tscan_build_kernel(
    const int* __restrict__ tdeg, int* __restrict__ tcursor,
    int* __restrict__ ctab, int* __restrict__ ccount)
{
    __shared__ int sdeg[100], soff[100];
    int tid = threadIdx.x;
    if (tid < 100) sdeg[tid] = tdeg[tid];
    __syncthreads();
    if (tid == 0) {
        int run = 0;
        for (int t = 0; t < 100; ++t) { soff[t] = run; run += sdeg[t]; }
    }
    __syncthreads();
    if (tid < 100) {
        tcursor[tid] = soff[tid];
        int cnt = sdeg[tid];
        int st = soff[tid];
        for (int ch = 0; ch*NCHK < cnt; ++ch) {
            int idx = atomicAdd(ccount, 1);
            int rem = cnt - ch*NCHK;
            ctab[idx*4+0] = st + ch*NCHK;
            ctab[idx*4+1] = (rem < NCHK) ? rem : NCHK;
            ctab[idx*4+2] = tid;
        }
    }
}

__global__ void tscatter_kernel(const int* __restrict__ types, int* __restrict__ tcursor,
                                int* __restrict__ nsorted)
{
    int n = blockIdx.x*256 + threadIdx.x;
    if (n >= NN) return;
    int p = atomicAdd(&tcursor[types[n]], 1);
    nsorted[p] = n;
}

// ---------------- fused edge kernel: geometry -> MFMA MLP chain -> TP -> segment-sum -> mid ----------------
// LDS ~15 KB. __launch_bounds__(256,6): measured best (r8/r10: 133us, occ 57%);
// (256,8) measured WORSE (r9: 144us, L2 thrash at occ 72%) -- do not raise.
// mid must be zeroed before launch (init_all for layer 0; node_update re-zeroes for l+1).
__global__ __launch_bounds__(256, 6) void edge_fused_kernel(
    const float* __restrict__ xp,
    const int* __restrict__ srcs, const int* __restrict__ dsts,
    const unsigned short* __restrict__ w1b,   // [64 n][32 k] bf16 (k 16..31 zero)
    const float* __restrict__ b1,
    const unsigned short* __restrict__ w2b,   // [64 n][64 k] bf16
    const float* __restrict__ b2,
    const unsigned short* __restrict__ w3b,   // [192 n][64 k] bf16
    const float* __restrict__ b3,
    const float* __restrict__ fs, const float* __restrict__ fvv,
    float* __restrict__ mid)
{
    __shared__ __align__(16) unsigned char smem[192*68];   // wbufT comp-major; hbuf aliases front
    __shared__ float abuf[6][68];                          // [half*3+m][e]
    __shared__ int ssrc[64], sdst[64];
    __shared__ unsigned smaskl[2];
    unsigned short* hbuf = (unsigned short*)smem;          // [64][72] bf16 (9216 B)
    int lane = threadIdx.x & 63;
    int wid  = threadIdx.x >> 6;
    int eblk = blockIdx.x * 64;
    int row16 = lane & 15, quad = lane >> 4;
    int erow = 16*wid + row16;

    // stage src/dst + boundary ballot (wave 0)
    if (threadIdx.x < 64) {
        int tid = threadIdx.x;
        int own = dsts[eblk + tid];
        ssrc[tid] = srcs[eblk + tid];
        int pidx = eblk + tid - ((tid > 0) ? 1 : 0);
        int prev = dsts[pidx];
        sdst[tid] = own;
        bool nb = (tid > 0) && (own != prev);
        unsigned long long bm = __ballot(nb);
        if (tid == 0) { smaskl[0] = (unsigned)bm; smaskl[1] = (unsigned)(bm >> 32); }
    }

    // ---- phase G (lanes 0..31): geometry ----
    if (lane < 32) {
        int eidx = 16*wid + (lane & 15);
        int half = lane >> 4;
        int p = eblk + eidx;
        int s = srcs[p], d = dsts[p];
        int off = 3*half;
        const float* xs = xp + (size_t)s*8 + off;
        const float* xd = xp + (size_t)d*8 + off;
        float d0 = xs[0]-xd[0], d1 = xs[1]-xd[1], d2 = xs[2]-xd[2];
        float r = sqrtf(d0*d0 + d1*d1 + d2*d2);
        float invr = 1.0f/r;
        float u = 0.8f*r - 2.0f;
        float cut = (u > 0.f) ? 0.f : ((u < -1.f) ? 1.f : 0.5f*(1.f - __cosf(PI_F*u)));
        float sc = 1.7320508075688772f*cut*invr;
        abuf[off+0][eidx] = sc*d0;
        abuf[off+1][eidx] = sc*d1;
        abuf[off+2][eidx] = sc*d2;
        float fsc = 2.5298221281347035f*invr;
        float wr = 1.2566370614359172f*r;
        unsigned epk[4];
        #pragma unroll
        for (int k = 0; k < 4; ++k) {
            float e0 = fsc*__sinf((float)(2*k+1)*wr);
            float e1 = fsc*__sinf((float)(2*k+2)*wr);
            epk[k] = (unsigned)f2b(e0) | ((unsigned)f2b(e1) << 16);
        }
        uint4* hr = (uint4*)(hbuf + eidx*72);
        uint4 q; q.x = epk[0]; q.y = epk[1]; q.z = epk[2]; q.w = epk[3];
        hr[half] = q;
        uint4 qz; qz.x = 0; qz.y = 0; qz.z = 0; qz.w = 0;
        hr[2+half] = qz;
    }
    // hbuf rows are wave-exclusive; per-wave DS ordering suffices for GEMM1/2

    // ---- GEMM1: h1 = silu(ef @ W1 + b1), K=32 ----
    {
        short8x a = *(const short8x*)(hbuf + erow*72 + quad*8);
        float4x c[4];
        #pragma unroll
        for (int nt = 0; nt < 4; ++nt) {
            short8x b = *(const short8x*)(w1b + ((size_t)(nt*16 + row16))*32 + quad*8);
            c[nt] = __builtin_amdgcn_mfma_f32_16x16x32_bf16(a, b, (float4x){0.f,0.f,0.f,0.f}, 0, 0, 0);
        }
        #pragma unroll
        for (int nt = 0; nt < 4; ++nt) {
            float bias = b1[nt*16 + row16];
            #pragma unroll
            for (int r = 0; r < 4; ++r) {
                float h = silu(c[nt][r] + bias);
                hbuf[(16*wid + quad*4 + r)*72 + nt*16 + row16] = f2b(h);
            }
        }
    }
    // ---- GEMM2: h2 = silu(h1 @ W2 + b2), K=64 ----
    {
        short8x a0v = *(const short8x*)(hbuf + erow*72 + 0*32 + quad*8);
        short8x a1v = *(const short8x*)(hbuf + erow*72 + 1*32 + quad*8);
        float4x c[4];
        #pragma unroll
        for (int nt = 0; nt < 4; ++nt) {
            short8x b0 = *(const short8x*)(w2b + ((size_t)(nt*16 + row16))*64 + 0*32 + quad*8);
            float4x t = __builtin_amdgcn_mfma_f32_16x16x32_bf16(a0v, b0, (float4x){0.f,0.f,0.f,0.f}, 0, 0, 0);
            short8x b1v = *(const short8x*)(w2b + ((size_t)(nt*16 + row16))*64 + 1*32 + quad*8);
            c[nt] = __builtin_amdgcn_mfma_f32_16x16x32_bf16(a1v, b1v, t, 0, 0, 0);
        }
        #pragma unroll
        for (int nt = 0; nt < 4; ++nt) {
            float bias = b2[nt*16 + row16];
            #pragma unroll
            for (int r = 0; r < 4; ++r) {
                float h = silu(c[nt][r] + bias);
                hbuf[(16*wid + quad*4 + r)*72 + nt*16 + row16] = f2b(h);
            }
        }
    }
    // ---- GEMM3: w = h2 @ W3 -> fp8 comp-major into wbufT (aliases hbuf; pre-read A then barrier) ----
    {
        short8x a0v = *(const short8x*)(hbuf + erow*72 + 0*32 + quad*8);
        short8x a1v = *(const short8x*)(hbuf + erow*72 + 1*32 + quad*8);
        __syncthreads();   // all waves hold their A-fragments; hbuf region may now be overwritten
        float4x acc[12];
        #pragma unroll
        for (int nt = 0; nt < 12; ++nt) {
            short8x b0 = *(const short8x*)(w3b + ((size_t)(nt*16 + row16))*64 + 0*32 + quad*8);
            float4x t = __builtin_amdgcn_mfma_f32_16x16x32_bf16(a0v, b0, (float4x){0.f,0.f,0.f,0.f}, 0, 0, 0);
            short8x b1v = *(const short8x*)(w3b + ((size_t)(nt*16 + row16))*64 + 1*32 + quad*8);
            acc[nt] = __builtin_amdgcn_mfma_f32_16x16x32_bf16(a1v, b1v, t, 0, 0, 0);
        }
        // lane holds comp = nt*16+row16, edges e = 16*wid + quad*4 + (0..3) -> one u32 store
        #pragma unroll
        for (int nt = 0; nt < 12; ++nt) {
            unsigned pw = pk4(acc[nt][0], acc[nt][1], acc[nt][2], acc[nt][3]);
            *(unsigned*)(smem + (size_t)(nt*16 + row16)*68 + 16*wid + quad*4) = pw;
        }
    }
    __syncthreads();

    // ---- TP + segment-sum phase ----
    {
        unsigned mk0 = __builtin_amdgcn_readfirstlane(smaskl[0]);
        unsigned mk1 = __builtin_amdgcn_readfirstlane(smaskl[1]);
        bool iso1 = (wid < 2);
        int h = iso1 ? wid : (wid - 2);
        unsigned mkh = (h ? mk1 : mk0) & ~1u;   // first edge of half never flushes
        int ebase = 32*h;
        int dcur = sdst[ebase];

        if (iso1) {
            // o1: u = lane; fs gathered wave-coalesced from global; 3 accumulators
            const unsigned char* wp = smem + (size_t)(2*lane)*68;
            float bA = b3[2*lane], bB = b3[2*lane+1];
            float acc0 = 0.f, acc1 = 0.f, acc2 = 0.f;
            #pragma unroll
            for (int ch = 0; ch < 8; ++ch) {
                int e4 = ebase + 4*ch;
                int4 sv = *(const int4*)&ssrc[e4];
                float f0 = fs[(size_t)sv.x*64 + lane];
                float f1 = fs[(size_t)sv.y*64 + lane];
                float f2 = fs[(size_t)sv.z*64 + lane];
                float f3 = fs[(size_t)sv.w*64 + lane];
                unsigned wa4 = *(const unsigned*)(wp + e4);
                unsigned wb4 = *(const unsigned*)(wp + 68 + e4);
                float4x a00 = *(const float4x*)(&abuf[0][e4]);
                float4x a01 = *(const float4x*)(&abuf[1][e4]);
                float4x a02 = *(const float4x*)(&abuf[2][e4]);
                float4x a10 = *(const float4x*)(&abuf[3][e4]);
                float4x a11 = *(const float4x*)(&abuf[4][e4]);
                float4x a12 = *(const float4x*)(&abuf[5][e4]);
                float fv[4] = {f0, f1, f2, f3};
                float q0[4], q1[4], q2[4];
                #pragma unroll
                for (int k = 0; k < 4; ++k) {
                    float f = fv[k];
                    float wa = (e4sel(wa4, k) + bA)*f;
                    float wb = (e4sel(wb4, k) + bB)*f;
                    q0[k] = wa*a00[k] + wb*a10[k];
                    q1[k] = wa*a01[k] + wb*a11[k];
                    q2[k] = wa*a02[k] + wb*a12[k];
                }
                unsigned mch = (mkh >> (4*ch)) & 15u;
                if (mch == 0) {
                    acc0 += (q0[0] + q0[1]) + (q0[2] + q0[3]);
                    acc1 += (q1[0] + q1[1]) + (q1[2] + q1[3]);
                    acc2 += (q2[0] + q2[1]) + (q2[2] + q2[3]);
                } else {
                    #pragma unroll
                    for (int k = 0; k < 4; ++k) {
                        if (mch & (1u << k)) {
                            float* mrow = mid + (size_t)dcur*256;
                            atomicAdd(mrow + 3*lane + 0, acc0*0.125f);
                            atomicAdd(mrow + 3*lane + 1, acc1*0.125f);
                            atomicAdd(mrow + 3*lane + 2, acc2*0.125f);
                            acc0 = acc1 = acc2 = 0.f;
                            dcur = sdst[e4 + k];
                        }
                        acc0 += q0[k]; acc1 += q1[k]; acc2 += q2[k];
                    }
                }
            }
            float* mrow = mid + (size_t)dcur*256;
            atomicAdd(mrow + 3*lane + 0, acc0*0.125f);
            atomicAdd(mrow + 3*lane + 1, acc1*0.125f);
            atomicAdd(mrow + 3*lane + 2, acc2*0.125f);
        } else {
            // unified o2/o3: fvv gathered from global; per-lane row offsets + sgn/gam
            bool iso2 = lane < 16;
            int j3 = lane - 16;
            int u3 = j3 / 3;
            int m3 = j3 - 3*u3;
            int m1 = (m3 == 2) ? 0 : (m3 + 1);
            int m2 = 3 - m3 - m1;
            const unsigned char* wp;
            int rA, rB, rC;
            const float* aX0; const float* aY0; const float* aZ0;
            const float* aX1; const float* aY1; const float* aZ1;
            float bA, bB, sgn, gam, FS;
            if (iso2) {
                wp = smem + (size_t)(128 + 2*lane)*68;
                bA = b3[128 + 2*lane]; bB = b3[129 + 2*lane];
                rA = 3*lane; rB = 3*lane + 1; rC = 3*lane + 2;
                aX0 = &abuf[0][0]; aY0 = &abuf[1][0]; aZ0 = &abuf[2][0];
                aX1 = &abuf[3][0]; aY1 = &abuf[4][0]; aZ1 = &abuf[5][0];
                sgn = 1.f; gam = 1.f; FS = 0.07216878364870323f;   // 1/sqrt(192)
            } else {
                wp = smem + (size_t)(160 + 2*u3)*68;
                bA = b3[160 + 2*u3]; bB = b3[161 + 2*u3];
                rA = 3*u3 + m1; rB = 3*u3 + m2; rC = 0;            // rC dummy (gam=0)
                aX0 = &abuf[m2][0]; aY0 = &abuf[m1][0]; aZ0 = &abuf[0][0];
                aX1 = &abuf[3+m2][0]; aY1 = &abuf[3+m1][0]; aZ1 = &abuf[3][0];
                sgn = -1.f; gam = 0.f; FS = 0.08838834764831845f;  // 1/sqrt(128)
            }
            int cb = 192 + lane;
            float accb = 0.f;
            #pragma unroll
            for (int ch = 0; ch < 8; ++ch) {
                int e4 = ebase + 4*ch;
                int4 sv = *(const int4*)&ssrc[e4];
                float fa0 = fvv[(size_t)sv.x*48 + rA];
                float fb0 = fvv[(size_t)sv.x*48 + rB];
                float fc0 = fvv[(size_t)sv.x*48 + rC];
                float fa1 = fvv[(size_t)sv.y*48 + rA];
                float fb1 = fvv[(size_t)sv.y*48 + rB];
                float fc1 = fvv[(size_t)sv.y*48 + rC];
                float fa2 = fvv[(size_t)sv.z*48 + rA];
                float fb2 = fvv[(size_t)sv.z*48 + rB];
                float fc2 = fvv[(size_t)sv.z*48 + rC];
                float fa3 = fvv[(size_t)sv.w*48 + rA];
                float fb3 = fvv[(size_t)sv.w*48 + rB];
                float fc3 = fvv[(size_t)sv.w*48 + rC];
                unsigned wa4 = *(const unsigned*)(wp + e4);
                unsigned wb4 = *(const unsigned*)(wp + 68 + e4);
                float4x x0 = *(const float4x*)(aX0 + e4);
                float4x y0 = *(const float4x*)(aY0 + e4);
                float4x z0 = *(const float4x*)(aZ0 + e4);
                float4x x1 = *(const float4x*)(aX1 + e4);
                float4x y1 = *(const float4x*)(aY1 + e4);
                float4x z1 = *(const float4x*)(aZ1 + e4);
                float fav[4] = {fa0, fa1, fa2, fa3};
                float fbv[4] = {fb0, fb1, fb2, fb3};
                float fcv[4] = {fc0, fc1, fc2, fc3};
                float q[4];
                #pragma unroll
                for (int k = 0; k < 4; ++k) {
                    float fa = fav[k], fb = fbv[k], fc = fcv[k];
                    float dA = fmaf(sgn, fb*y0[k], fa*x0[k]);
                    dA = fmaf(gam, fc*z0[k], dA);
                    float dB = fmaf(sgn, fb*y1[k], fa*x1[k]);
                    dB = fmaf(gam, fc*z1[k], dB);
                    q[k] = (e4sel(wa4, k) + bA)*dA + (e4sel(wb4, k) + bB)*dB;
                }
                unsigned mch = (mkh >> (4*ch)) & 15u;
                if (mch == 0) {
                    accb += (q[0] + q[1]) + (q[2] + q[3]);
                } else {
                    #pragma unroll
                    for (int k = 0; k < 4; ++k) {
                        if (mch & (1u << k)) {
                            atomicAdd(mid + (size_t)dcur*256 + cb, accb*FS);
                            accb = 0.f;
                            dcur = sdst[e4 + k];
                        }
                        accb += q[k];
                    }
                }
            }
            atomicAdd(mid + (size_t)dcur*256 + cb, accb*FS);
        }
    }
}

// ---------------- node update, type-batched: stage per-type weights in LDS, 8 nodes/block ----------------
// Blocks read (start,count,type) from ctab; per-type weight tables (scsT/lin2sT/scvT/lin2vT/
// lin1sTn/lin1vTn = 48KB) staged ONCE and reused across the chunk's nodes. Per-node math is
// bitwise identical to the previous per-node kernel. Re-zeroes mid rows for the next layer.
__global__ __launch_bounds__(256) void node_update_kernel(
    const float* __restrict__ ys, const float* __restrict__ yv,
    float* __restrict__ ys_old, float* __restrict__ yv_old,
    float* __restrict__ mid,
    const float* __restrict__ scsT, const float* __restrict__ scvT,
    const float* __restrict__ lin2sT, const float* __restrict__ lin2vT,
    const float* __restrict__ siWsT, const float* __restrict__ siWvT,
    const float* __restrict__ lin1sTn, const float* __restrict__ lin1vTn, // next layer
    const float* __restrict__ Kbuf,
    const float* __restrict__ hv, const float* __restrict__ mixv, int layer,
    float* __restrict__ fs_out, float* __restrict__ fvv_out,
    float* __restrict__ xpad, float* __restrict__ dout,
    const int* __restrict__ nsorted, const int* __restrict__ ctab)
{
    int bid = blockIdx.x;
    int start = ctab[bid*4+0];
    int cnt   = ctab[bid*4+1];
    int t     = ctab[bid*4+2];
    if (cnt == 0) return;
    __shared__ float wl[12288];    // 48 KB per-type weights
    __shared__ float ys_l[64], yv_l[48], mids[16], midv[240];
    __shared__ float conv_s[80], conv_v[48], sis_l[64], siv_l[48], ysn[64], yvn[48];
    int lane = threadIdx.x;
    {   // stage per-type weights (float4, coalesced)
        float4* d = (float4*)wl;
        const float4* s0 = (const float4*)(scsT + (size_t)t*5120);
        for (int i = lane; i < 1280; i += 256) d[i] = s0[i];
        const float4* s1 = (const float4*)(lin2sT + (size_t)t*1280);
        for (int i = lane; i < 320; i += 256) d[1280 + i] = s1[i];
        const float4* s2 = (const float4*)(scvT + (size_t)t*256);
        if (lane < 64) d[1600 + lane] = s2[lane];
        const float4* s3 = (const float4*)(lin2vT + (size_t)t*1280);
        for (int i = lane; i < 320; i += 256) d[1664 + i] = s3[i];
        const float4* s4 = (const float4*)(lin1sTn + (size_t)t*4096);
        for (int i = lane; i < 1024; i += 256) d[1984 + i] = s4[i];
        const float4* s5 = (const float4*)(lin1vTn + (size_t)t*256);
        if (lane < 64) d[3008 + lane] = s5[lane];
    }
    const float* sWsc = wl;          // [64][80]
    const float* sW2s = wl + 5120;   // [16][80]
    const float* sWcv = wl + 6400;   // [16][16]
    const float* sW2v = wl + 6656;   // [80][16]
    const float* sL1s = wl + 7936;   // [64][64]
    const float* sL1v = wl + 12032;  // [16][16]
    float hh = hv[layer]; float h2c = hh*hh; float mx = mixv[layer];
    __syncthreads();

    for (int ni = 0; ni < cnt; ++ni) {
        int n = nsorted[start + ni];
        {
            float v = mid[(size_t)n*256 + lane];
            mid[(size_t)n*256 + lane] = 0.f;     // zero for next layer
            if (lane < 192) midv[lane] = v;
            else if (lane < 208) mids[lane-192] = v;
            else midv[192 + (lane-208)] = v;
        }
        if (lane < 64) ys_l[lane] = ys[n*64 + lane];
        else if (lane < 112) yv_l[lane-64] = yv[n*48 + (lane-64)];
        __syncthreads();
        if (lane < 80) {
            float a_sc = 0.f, a_2 = 0.f;
            #pragma unroll
            for (int i = 0; i < 64; ++i) a_sc += ys_l[i]*sWsc[i*80 + lane];
            #pragma unroll
            for (int i = 0; i < 16; ++i) a_2 += mids[i]*sW2s[i*80 + lane];
            conv_s[lane] = 0.3826834323650898f*a_sc + 0.9238795325112867f*a_2;
        } else if (lane < 144) {
            int o = lane - 80;
            float a_si = 0.f;
            #pragma unroll
            for (int i = 0; i < 64; ++i) a_si += ys_l[i]*siWsT[i*64 + o];
            sis_l[o] = a_si;
        } else if (lane < 192) {
            int j = lane - 144, o = j/3, m = j%3;
            float a_sc = 0.f, a_2 = 0.f, a_si = 0.f;
            #pragma unroll
            for (int i = 0; i < 16; ++i) {
                float y = yv_l[i*3+m];
                a_sc += y*sWcv[i*16+o];
                a_si += y*siWvT[i*16+o];
            }
            #pragma unroll
            for (int i = 0; i < 80; ++i) a_2 += midv[i*3+m]*sW2v[i*16+o];
            conv_v[j] = 0.3826834323650898f*a_sc + 0.9238795325112867f*a_2;
            siv_l[j] = a_si;
        }
        __syncthreads();
        if (lane < 64) {
            float cs = conv_s[lane];
            float gns = cs/(1.f + __expf(-cs));
            float ns = 2.f*ys_l[lane] - ys_old[n*64+lane] + h2c*(mx*gns + (mx-1.f)*sis_l[lane]);
            ys_old[n*64+lane] = ns;
            ysn[lane] = ns;
        } else if (lane < 112) {
            int j = lane-64, o = j/3;
            float g = 1.f/(1.f + __expf(-conv_s[64+o]));
            float gnv = g*conv_v[j];
            float nv = 2.f*yv_l[j] - yv_old[n*48+j] + h2c*(mx*gnv + (mx-1.f)*siv_l[j]);
            yv_old[n*48+j] = nv;
            yvn[j] = nv;
        }
        __syncthreads();
        if (lane < 6) {
            int i = lane/3, m = lane%3;
            float acc = 0.f;
            #pragma unroll
            for (int u = 0; u < 16; ++u) acc += Kbuf[2*u+i]*yvn[u*3+m];
            xpad[n*8 + lane] = acc;
            if (dout) dout[n*6 + lane] = acc;
        }
        // fused next-layer lin1
        if (lane < 64) {
            float acc = 0.f;
            #pragma unroll
            for (int i = 0; i < 64; ++i) acc += ysn[i]*sL1s[i*64 + lane];
            fs_out[n*64 + lane] = acc;
        } else if (lane < 112) {
            int j = lane - 64, o = j/3, m = j%3;
            float acc = 0.f;
            #pragma unroll
            for (int i = 0; i < 16; ++i) acc += yvn[i*3+m]*sL1v[i*16 + o];
            fvv_out[n*48 + j] = acc;
        }
        __syncthreads();   // protect shared arrays before next node's writes
    }
}

// ---------------- host ----------------
extern "C" void kernel_launch(void* const* d_in, const int* in_sizes, int n_in,
                              void* d_out, int out_size, void* d_ws, size_t ws_size,
                              hipStream_t stream)
{
    const float* x_in   = (const float*)d_in[0];
    const int*   types  = (const int*)  d_in[2];
    const int*   esrc   = (const int*)  d_in[3];
    const int*   edst   = (const int*)  d_in[4];
    const float* emb    = (const float*)d_in[5];
    const float* PU     = (const float*)d_in[6];
    const float* hv     = (const float*)d_in[7];
    const float* mixv   = (const float*)d_in[8];
    const float* si_Ws  = (const float*)d_in[9];
    const float* si_Wv  = (const float*)d_in[10];
    const float* sc_Ws  = (const float*)d_in[11];
    const float* sc_Wv  = (const float*)d_in[12];
    const float* lin1_Ws= (const float*)d_in[13];
    const float* lin1_Wv= (const float*)d_in[14];
    const float* lin2_Ws= (const float*)d_in[15];
    const float* lin2_Wv= (const float*)d_in[16];
    const float* fc_W1  = (const float*)d_in[17];
    const float* fc_b1  = (const float*)d_in[18];
    const float* fc_W2  = (const float*)d_in[19];
    const float* fc_b2  = (const float*)d_in[20];
    const float* fc_W3  = (const float*)d_in[21];
    const float* fc_b3  = (const float*)d_in[22];

    float* ws = (float*)d_ws;
    size_t off = 0;
    auto alloc = [&](size_t nf) { float* p = ws + off; off += nf; return p; };
    float* Kbuf   = alloc(64);
    float* x_pad  = alloc(80000);
    float* ys0    = alloc(640000);
    float* ys1    = alloc(640000);
    float* yv0    = alloc(480000);
    float* yv1    = alloc(480000);
    float* fsb    = alloc(640000);
    float* fvvb   = alloc(480000);
    float* midb   = alloc((size_t)NN*256);
    float* lin1sT = alloc((size_t)4*100*4096);
    float* lin1vT = alloc((size_t)4*100*256);
    float* scsT   = alloc((size_t)4*100*5120);
    float* scvT   = alloc((size_t)4*100*256);
    float* lin2sT = alloc((size_t)4*100*1280);
    float* lin2vT = alloc((size_t)4*100*1280);
    float* siWsT  = alloc((size_t)4*4096);
    float* siWvT  = alloc((size_t)4*256);
    // int region
    int* iws = (int*)(ws + off);
    size_t ioff = 0;
    auto ialloc = [&](size_t ni) { int* p = iws + ioff; ioff += ni; return p; };
    int* deg    = ialloc(NN);
    int* segoff = ialloc(NN + 8);
    int* cursor = ialloc(NN);
    int* srcs   = ialloc(NE);
    int* dsts   = ialloc(NE);
    // node-type sort region (tdeg..ccnt contiguous -> one memset)
    int* tdeg    = ialloc(104);
    int* tcursor = ialloc(104);
    int* ctabi   = ialloc(MAXCH*4);
    int* ccnt    = ialloc(4);
    int* nsorted = ialloc(NN);
    // bf16 region (16B-aligned)
    unsigned short* w1bp = (unsigned short*)(iws + ioff);   // [L][64][32]
    unsigned short* w2bp = w1bp + (size_t)4*64*32;          // [L][64][64]
    unsigned short* w3bf = w2bp + (size_t)4*64*64;          // [L][192][64]

    // K + weight prep + state init
    k_newton_kernel<<<1, 1, 0, stream>>>(PU, Kbuf);
    prep_kernel<<<(PREP_TOTAL + 255)/256, 256, 0, stream>>>(
        lin1_Ws, lin1_Wv, sc_Ws, sc_Wv, lin2_Ws, lin2_Wv, si_Ws, si_Wv,
        fc_W1, fc_W2, fc_W3, emb,
        lin1sT, lin1vT, scsT, scvT, lin2sT, lin2vT, siWsT, siWvT,
        w1bp, w2bp, w3bf);
    {
        int tot = NN*8 + NN*48 + NN*64 + NN*256;
        init_all_kernel<<<(tot + 255)/256, 256, 0, stream>>>(
            x_in, Kbuf, x_pad, yv0, yv1, ys0, ys1, fsb, midb);
    }
    init_fvv_kernel<<<(NN*48 + 255)/256, 256, 0, stream>>>(yv0, types, lin1vT, fvvb);

    // counting sort of edges by dst
    (void)hipMemsetAsync(deg, 0, NN*sizeof(int), stream);
    hist_kernel<<<(NE+255)/256, 256, 0, stream>>>(edst, deg);
    scan_kernel<<<1, 256, 0, stream>>>(deg, segoff, cursor);
    scatter_kernel<<<(NE+255)/256, 256, 0, stream>>>(esrc, edst, cursor, srcs, dsts);

    // counting sort of nodes by type + chunk table
    (void)hipMemsetAsync(tdeg, 0, (104 + 104 + MAXCH*4 + 4)*sizeof(int), stream);
    thist_kernel<<<(NN+255)/256, 256, 0, stream>>>(types, tdeg);
    tscan_build_kernel<<<1, 128, 0, stream>>>(tdeg, tcursor, ctabi, ccnt);
    tscatter_kernel<<<(NN+255)/256, 256, 0, stream>>>(types, tcursor, nsorted);

    float* ys_cur = ys0; float* ys_old = ys1;
    float* yv_cur = yv0; float* yv_old = yv1;
    for (int l = 0; l < 4; ++l) {
        edge_fused_kernel<<<NE/64, 256, 0, stream>>>(
            x_pad, srcs, dsts,
            w1bp + (size_t)l*64*32,  fc_b1 + (size_t)l*64,
            w2bp + (size_t)l*64*64,  fc_b2 + (size_t)l*64,
            w3bf + (size_t)l*192*64, fc_b3 + (size_t)l*192,
            fsb, fvvb, midb);
        int ln = (l + 1) & 3;   // next-layer lin1 weights (l=3: dummy but valid)
        node_update_kernel<<<MAXCH, 256, 0, stream>>>(
            ys_cur, yv_cur, ys_old, yv_old,
            midb,
            scsT   + (size_t)l*100*5120, scvT   + (size_t)l*100*256,
            lin2sT + (size_t)l*100*1280, lin2vT + (size_t)l*100*1280,
            siWsT  + (size_t)l*4096,     siWvT  + (size_t)l*256,
            lin1sT + (size_t)ln*100*4096, lin1vT + (size_t)ln*100*256,
            Kbuf, hv, mixv, l, fsb, fvvb,
            x_pad, (l == 3) ? (float*)d_out : nullptr,
            nsorted, ctabi);
        float* tmp;
        tmp = ys_cur; ys_cur = ys_old; ys_old = tmp;
        tmp = yv_cur; yv_cur = yv_old; yv_old = tmp;
    }
}

// Round 13
// 972.648 us; speedup vs baseline: 1.9687x; 1.9687x over previous
//
#include <hip/hip_runtime.h>
#include <hip/hip_fp8.h>
#include <math.h>

#define NN 10000
#define NE 320000
#define PI_F 3.14159265358979323846f

typedef __attribute__((ext_vector_type(8))) short short8x;
typedef __attribute__((ext_vector_type(4))) float float4x;

#if defined(__has_builtin)
#if __has_builtin(__builtin_amdgcn_cvt_pk_fp8_f32) && __has_builtin(__builtin_amdgcn_cvt_f32_fp8)
#define HW_FP8 1
#endif
#endif

__device__ __forceinline__ unsigned short f2b(float f) {
    unsigned b = __float_as_uint(f);
    return (unsigned short)((b + 0x7FFFu + ((b >> 16) & 1u)) >> 16);
}
__device__ __forceinline__ float b2f(unsigned short u) {
    return __uint_as_float(((unsigned)u) << 16);
}
__device__ __forceinline__ float silu(float x) {
    return x / (1.f + __expf(-x));
}
__device__ __forceinline__ unsigned char f2e4(float f) {
#ifdef HW_FP8
    int r = __builtin_amdgcn_cvt_pk_fp8_f32(f, f, 0, false);
    return (unsigned char)(r & 0xff);
#else
    __hip_fp8_e4m3 q(f);
    return (unsigned char)q.__x;
#endif
}
__device__ __forceinline__ float e42f(unsigned char v) {
#ifdef HW_FP8
    return __builtin_amdgcn_cvt_f32_fp8((int)v, 0);
#else
    __hip_fp8_e4m3 q;
    q.__x = (__hip_fp8_storage_t)v;
    return (float)q;
#endif
}
// byte-select decode: builtin requires IMMEDIATE sel -> switch with literal cases
__device__ __forceinline__ float e4sel(unsigned word, int sel) {
#ifdef HW_FP8
    switch (sel & 3) {
        case 0:  return __builtin_amdgcn_cvt_f32_fp8((int)word, 0);
        case 1:  return __builtin_amdgcn_cvt_f32_fp8((int)word, 1);
        case 2:  return __builtin_amdgcn_cvt_f32_fp8((int)word, 2);
        default: return __builtin_amdgcn_cvt_f32_fp8((int)word, 3);
    }
#else
    return e42f((unsigned char)((word >> (8*(sel & 3))) & 0xffu));
#endif
}
__device__ __forceinline__ unsigned pk4(float a, float b, float c, float d) {
#ifdef HW_FP8
    unsigned w = (unsigned)__builtin_amdgcn_cvt_pk_fp8_f32(a, b, 0, false);
    w = (unsigned)__builtin_amdgcn_cvt_pk_fp8_f32(c, d, (int)w, true);
    return w;
#else
    return (unsigned)f2e4(a) | ((unsigned)f2e4(b) << 8) |
           ((unsigned)f2e4(c) << 16) | ((unsigned)f2e4(d) << 24);
#endif
}

// ---------------- K = Newton-Schulz semi-unitary (16x2) ----------------
__global__ void k_newton_kernel(const float* __restrict__ PU, float* __restrict__ Kout)
{
    if (threadIdx.x != 0 || blockIdx.x != 0) return;
    float K[32];
    float nrm = 0.f;
    for (int i = 0; i < 32; ++i) { K[i] = PU[i]; nrm += K[i]*K[i]; }
    float inv = 1.0f / sqrtf(nrm);
    for (int i = 0; i < 32; ++i) K[i] *= inv;
    for (int it = 0; it < 10; ++it) {
        float m00 = 0.f, m01 = 0.f, m11 = 0.f;
        for (int u = 0; u < 16; ++u) {
            float a = K[2*u], b = K[2*u+1];
            m00 += a*a; m01 += a*b; m11 += b*b;
        }
        for (int u = 0; u < 16; ++u) {
            float a = K[2*u], b = K[2*u+1];
            K[2*u]   = 1.5f*a - 0.5f*(a*m00 + b*m01);
            K[2*u+1] = 1.5f*b - 0.5f*(a*m01 + b*m11);
        }
    }
    for (int i = 0; i < 32; ++i) Kout[i] = K[i];
}

// ---------------- merged init: x_pad + yv init + zero ys0/ys1/fsb + zero midb ----------------
__global__ __launch_bounds__(256) void init_all_kernel(
    const float* __restrict__ x, const float* __restrict__ K,
    float* __restrict__ xp, float* __restrict__ yv0, float* __restrict__ yv1,
    float* __restrict__ ys0, float* __restrict__ ys1, float* __restrict__ fsb,
    float* __restrict__ midb)
{
    int tid = blockIdx.x*256 + threadIdx.x;
    if (tid < NN*8) {
        int n = tid >> 3, c = tid & 7;
        xp[tid] = (c < 6) ? x[n*6 + c] : 0.f;
        return;
    }
    int t2 = tid - NN*8;
    if (t2 < NN*48) {
        int n = t2/48, j = t2%48, u = j/3, m = j%3;
        float v = K[2*u]*x[n*6+m] + K[2*u+1]*x[n*6+3+m];
        yv0[t2] = v; yv1[t2] = v;
        return;
    }
    t2 -= NN*48;
    if (t2 < NN*64) { ys0[t2] = 0.f; ys1[t2] = 0.f; fsb[t2] = 0.f; return; }
    t2 -= NN*64;
    if (t2 < NN*256) midb[t2] = 0.f;
}

// ---------------- layer-0 fvv init (fs0 = 0 since ys0 = 0) ----------------
__global__ void init_fvv_kernel(const float* __restrict__ yv, const int* __restrict__ types,
                                const float* __restrict__ lin1vT0, float* __restrict__ fvv)
{
    int tid = blockIdx.x*blockDim.x + threadIdx.x;
    if (tid >= NN*48) return;
    int n = tid/48, j = tid%48, o = j/3, m = j%3;
    int t = types[n];
    const float* W = lin1vT0 + (size_t)t*256;
    float acc = 0.f;
    #pragma unroll
    for (int i = 0; i < 16; ++i) acc += yv[n*48 + i*3 + m]*W[i*16 + o];
    fvv[tid] = acc;
}

// ---------------- per-type effective weights (device body) ----------------
__device__ __forceinline__ void be_body(const float* __restrict__ W, const float* __restrict__ emb,
                                        float* __restrict__ out, int id, int O, int I, float scale)
{
    int o = id % O; int r = id / O;
    int i = r % I; r /= I;
    int t = r % 100; int l = r / 100;
    const float* w  = W + (((size_t)l*O + o)*I + i)*32;
    const float* em = emb + (size_t)t*32;
    float acc = 0.f;
    #pragma unroll
    for (int e = 0; e < 32; ++e) acc += w[e]*em[e];
    out[id] = acc*scale;
}

// ---------------- merged weight prep ----------------
#define PREP_TOTAL (2048000 + 1638400 + 512000 + 512000 + 102400 + 102400 + 49152 + 16384 + 16384 + 8192 + 1024)
__global__ __launch_bounds__(256) void prep_kernel(
    const float* __restrict__ lin1_Ws, const float* __restrict__ lin1_Wv,
    const float* __restrict__ sc_Ws,   const float* __restrict__ sc_Wv,
    const float* __restrict__ lin2_Ws, const float* __restrict__ lin2_Wv,
    const float* __restrict__ si_Ws,   const float* __restrict__ si_Wv,
    const float* __restrict__ fc_W1,   const float* __restrict__ fc_W2,
    const float* __restrict__ fc_W3,   const float* __restrict__ emb,
    float* __restrict__ lin1sT, float* __restrict__ lin1vT,
    float* __restrict__ scsT,   float* __restrict__ scvT,
    float* __restrict__ lin2sT, float* __restrict__ lin2vT,
    float* __restrict__ siWsT,  float* __restrict__ siWvT,
    unsigned short* __restrict__ w1bp, unsigned short* __restrict__ w2bp,
    unsigned short* __restrict__ w3bf)
{
    const float s2048 = 0.022097086912079608f;   // 1/sqrt(2048)
    const float s512  = 0.044194173824159216f;   // 1/sqrt(512)
    const float s2560 = 0.019764235376052372f;   // 1/sqrt(2560)
    int tid = blockIdx.x*256 + threadIdx.x;
    if (tid < 2048000) { be_body(sc_Ws,   emb, scsT,   tid, 80, 64, s2048); return; }
    tid -= 2048000;
    if (tid < 1638400) { be_body(lin1_Ws, emb, lin1sT, tid, 64, 64, s2048); return; }
    tid -= 1638400;
    if (tid < 512000)  { be_body(lin2_Ws, emb, lin2sT, tid, 80, 16, s512);  return; }
    tid -= 512000;
    if (tid < 512000)  { be_body(lin2_Wv, emb, lin2vT, tid, 16, 80, s2560); return; }
    tid -= 512000;
    if (tid < 102400)  { be_body(lin1_Wv, emb, lin1vT, tid, 16, 16, s512);  return; }
    tid -= 102400;
    if (tid < 102400)  { be_body(sc_Wv,   emb, scvT,   tid, 16, 16, s512);  return; }
    tid -= 102400;
    if (tid < 49152) {  // w3bf = bf16(transpose(fc_W3)): [l][n=192][k=64]
        int o = tid % 64; int r = tid / 64; int i = r % 192; int l = r / 192;
        w3bf[tid] = f2b(fc_W3[((size_t)l*64 + o)*192 + i]);
        return;
    }
    tid -= 49152;
    if (tid < 16384) {  // siWsT = 0.125 * transpose(si_Ws)
        int o = tid % 64; int r = tid / 64; int i = r % 64; int l = r / 64;
        siWsT[tid] = si_Ws[((size_t)l*64 + o)*64 + i]*0.125f;
        return;
    }
    tid -= 16384;
    if (tid < 16384) {  // w2bp: pack fc_W2 K=64,N=64,KP=64
        int kk = tid % 64; int r = tid / 64; int n = r % 64; int l = r / 64;
        w2bp[tid] = f2b(fc_W2[((size_t)l*64 + kk)*64 + n]);
        return;
    }
    tid -= 16384;
    if (tid < 8192) {   // w1bp: pack fc_W1 K=16,N=64,KP=32 (zero-pad)
        int kk = tid % 32; int r = tid / 32; int n = r % 64; int l = r / 64;
        float v = (kk < 16) ? fc_W1[((size_t)l*16 + kk)*64 + n] : 0.f;
        w1bp[tid] = f2b(v);
        return;
    }
    tid -= 8192;
    if (tid < 1024) {   // siWvT = 0.25 * transpose(si_Wv)
        int o = tid % 16; int r = tid / 16; int i = r % 16; int l = r / 16;
        siWvT[tid] = si_Wv[((size_t)l*16 + o)*16 + i]*0.25f;
    }
}

// ---------------- counting sort of edges by dst ----------------
__global__ void hist_kernel(const int* __restrict__ dst, int* __restrict__ deg)
{
    int e = blockIdx.x*256 + threadIdx.x;
    if (e < NE) atomicAdd(&deg[dst[e]], 1);
}

__global__ __launch_bounds__(256) void scan_kernel(const int* __restrict__ deg,
                                                   int* __restrict__ segoff,
                                                   int* __restrict__ cursor)
{
    __shared__ int part[256];
    int tid = threadIdx.x;
    int base = tid*40;
    int s = 0;
    for (int i = 0; i < 40; ++i) { int idx = base+i; if (idx < NN) s += deg[idx]; }
    part[tid] = s;
    __syncthreads();
    for (int o = 1; o < 256; o <<= 1) {
        int v = (tid >= o) ? part[tid-o] : 0;
        __syncthreads();
        part[tid] += v;
        __syncthreads();
    }
    int excl = part[tid] - s;
    for (int i = 0; i < 40; ++i) {
        int idx = base+i;
        if (idx < NN) { segoff[idx] = excl; cursor[idx] = excl; excl += deg[idx]; }
        else if (idx == NN) { segoff[NN] = excl; }
    }
}

__global__ void scatter_kernel(const int* __restrict__ src, const int* __restrict__ dst,
                               int* __restrict__ cursor,
                               int* __restrict__ srcs, int* __restrict__ dsts)
{
    int e = blockIdx.x*256 + threadIdx.x;
    if (e >= NE) return;
    int d = dst[e];
    int p = atomicAdd(&cursor[d], 1);
    srcs[p] = src[e]; dsts[p] = d;
}

// ---------------- counting sort of nodes by type (for L2-friendly block ordering) ----------------
__global__ void thist_kernel(const int* __restrict__ types, int* __restrict__ tdeg)
{
    int n = blockIdx.x*256 + threadIdx.x;
    if (n < NN) atomicAdd(&tdeg[types[n]], 1);
}

__global__ __launch_bounds__(128) void tscan_kernel(const int* __restrict__ tdeg,
                                                    int* __restrict__ tcursor)
{
    if (threadIdx.x != 0 || blockIdx.x != 0) return;
    int run = 0;
    for (int t = 0; t < 100; ++t) { tcursor[t] = run; run += tdeg[t]; }
}

__global__ void tscatter_kernel(const int* __restrict__ types, int* __restrict__ tcursor,
                                int* __restrict__ nsorted)
{
    int n = blockIdx.x*256 + threadIdx.x;
    if (n >= NN) return;
    int p = atomicAdd(&tcursor[types[n]], 1);
    nsorted[p] = n;
}

// ---------------- fused edge kernel: geometry -> MFMA MLP chain -> TP -> segment-sum -> mid ----------------
// LDS ~15 KB. __launch_bounds__(256,6): measured best (r8/r10: 133us, occ 57%);
// (256,8) measured WORSE (r9: 144us, L2 thrash at occ 72%) -- do not raise.
// mid must be zeroed before launch (init_all for layer 0; node_update re-zeroes for l+1).
__global__ __launch_bounds__(256, 6) void edge_fused_kernel(
    const float* __restrict__ xp,
    const int* __restrict__ srcs, const int* __restrict__ dsts,
    const unsigned short* __restrict__ w1b,   // [64 n][32 k] bf16 (k 16..31 zero)
    const float* __restrict__ b1,
    const unsigned short* __restrict__ w2b,   // [64 n][64 k] bf16
    const float* __restrict__ b2,
    const unsigned short* __restrict__ w3b,   // [192 n][64 k] bf16
    const float* __restrict__ b3,
    const float* __restrict__ fs, const float* __restrict__ fvv,
    float* __restrict__ mid)
{
    __shared__ __align__(16) unsigned char smem[192*68];   // wbufT comp-major; hbuf aliases front
    __shared__ float abuf[6][68];                          // [half*3+m][e]
    __shared__ int ssrc[64], sdst[64];
    __shared__ unsigned smaskl[2];
    unsigned short* hbuf = (unsigned short*)smem;          // [64][72] bf16 (9216 B)
    int lane = threadIdx.x & 63;
    int wid  = threadIdx.x >> 6;
    int eblk = blockIdx.x * 64;
    int row16 = lane & 15, quad = lane >> 4;
    int erow = 16*wid + row16;

    // stage src/dst + boundary ballot (wave 0)
    if (threadIdx.x < 64) {
        int tid = threadIdx.x;
        int own = dsts[eblk + tid];
        ssrc[tid] = srcs[eblk + tid];
        int pidx = eblk + tid - ((tid > 0) ? 1 : 0);
        int prev = dsts[pidx];
        sdst[tid] = own;
        bool nb = (tid > 0) && (own != prev);
        unsigned long long bm = __ballot(nb);
        if (tid == 0) { smaskl[0] = (unsigned)bm; smaskl[1] = (unsigned)(bm >> 32); }
    }

    // ---- phase G (lanes 0..31): geometry ----
    if (lane < 32) {
        int eidx = 16*wid + (lane & 15);
        int half = lane >> 4;
        int p = eblk + eidx;
        int s = srcs[p], d = dsts[p];
        int off = 3*half;
        const float* xs = xp + (size_t)s*8 + off;
        const float* xd = xp + (size_t)d*8 + off;
        float d0 = xs[0]-xd[0], d1 = xs[1]-xd[1], d2 = xs[2]-xd[2];
        float r = sqrtf(d0*d0 + d1*d1 + d2*d2);
        float invr = 1.0f/r;
        float u = 0.8f*r - 2.0f;
        float cut = (u > 0.f) ? 0.f : ((u < -1.f) ? 1.f : 0.5f*(1.f - __cosf(PI_F*u)));
        float sc = 1.7320508075688772f*cut*invr;
        abuf[off+0][eidx] = sc*d0;
        abuf[off+1][eidx] = sc*d1;
        abuf[off+2][eidx] = sc*d2;
        float fsc = 2.5298221281347035f*invr;
        float wr = 1.2566370614359172f*r;
        unsigned epk[4];
        #pragma unroll
        for (int k = 0; k < 4; ++k) {
            float e0 = fsc*__sinf((float)(2*k+1)*wr);
            float e1 = fsc*__sinf((float)(2*k+2)*wr);
            epk[k] = (unsigned)f2b(e0) | ((unsigned)f2b(e1) << 16);
        }
        uint4* hr = (uint4*)(hbuf + eidx*72);
        uint4 q; q.x = epk[0]; q.y = epk[1]; q.z = epk[2]; q.w = epk[3];
        hr[half] = q;
        uint4 qz; qz.x = 0; qz.y = 0; qz.z = 0; qz.w = 0;
        hr[2+half] = qz;
    }
    // hbuf rows are wave-exclusive; per-wave DS ordering suffices for GEMM1/2

    // ---- GEMM1: h1 = silu(ef @ W1 + b1), K=32 ----
    {
        short8x a = *(const short8x*)(hbuf + erow*72 + quad*8);
        float4x c[4];
        #pragma unroll
        for (int nt = 0; nt < 4; ++nt) {
            short8x b = *(const short8x*)(w1b + ((size_t)(nt*16 + row16))*32 + quad*8);
            c[nt] = __builtin_amdgcn_mfma_f32_16x16x32_bf16(a, b, (float4x){0.f,0.f,0.f,0.f}, 0, 0, 0);
        }
        #pragma unroll
        for (int nt = 0; nt < 4; ++nt) {
            float bias = b1[nt*16 + row16];
            #pragma unroll
            for (int r = 0; r < 4; ++r) {
                float h = silu(c[nt][r] + bias);
                hbuf[(16*wid + quad*4 + r)*72 + nt*16 + row16] = f2b(h);
            }
        }
    }
    // ---- GEMM2: h2 = silu(h1 @ W2 + b2), K=64 ----
    {
        short8x a0v = *(const short8x*)(hbuf + erow*72 + 0*32 + quad*8);
        short8x a1v = *(const short8x*)(hbuf + erow*72 + 1*32 + quad*8);
        float4x c[4];
        #pragma unroll
        for (int nt = 0; nt < 4; ++nt) {
            short8x b0 = *(const short8x*)(w2b + ((size_t)(nt*16 + row16))*64 + 0*32 + quad*8);
            float4x t = __builtin_amdgcn_mfma_f32_16x16x32_bf16(a0v, b0, (float4x){0.f,0.f,0.f,0.f}, 0, 0, 0);
            short8x b1v = *(const short8x*)(w2b + ((size_t)(nt*16 + row16))*64 + 1*32 + quad*8);
            c[nt] = __builtin_amdgcn_mfma_f32_16x16x32_bf16(a1v, b1v, t, 0, 0, 0);
        }
        #pragma unroll
        for (int nt = 0; nt < 4; ++nt) {
            float bias = b2[nt*16 + row16];
            #pragma unroll
            for (int r = 0; r < 4; ++r) {
                float h = silu(c[nt][r] + bias);
                hbuf[(16*wid + quad*4 + r)*72 + nt*16 + row16] = f2b(h);
            }
        }
    }
    // ---- GEMM3: w = h2 @ W3 -> fp8 comp-major into wbufT (aliases hbuf; pre-read A then barrier) ----
    {
        short8x a0v = *(const short8x*)(hbuf + erow*72 + 0*32 + quad*8);
        short8x a1v = *(const short8x*)(hbuf + erow*72 + 1*32 + quad*8);
        __syncthreads();   // all waves hold their A-fragments; hbuf region may now be overwritten
        float4x acc[12];
        #pragma unroll
        for (int nt = 0; nt < 12; ++nt) {
            short8x b0 = *(const short8x*)(w3b + ((size_t)(nt*16 + row16))*64 + 0*32 + quad*8);
            float4x t = __builtin_amdgcn_mfma_f32_16x16x32_bf16(a0v, b0, (float4x){0.f,0.f,0.f,0.f}, 0, 0, 0);
            short8x b1v = *(const short8x*)(w3b + ((size_t)(nt*16 + row16))*64 + 1*32 + quad*8);
            acc[nt] = __builtin_amdgcn_mfma_f32_16x16x32_bf16(a1v, b1v, t, 0, 0, 0);
        }
        // lane holds comp = nt*16+row16, edges e = 16*wid + quad*4 + (0..3) -> one u32 store
        #pragma unroll
        for (int nt = 0; nt < 12; ++nt) {
            unsigned pw = pk4(acc[nt][0], acc[nt][1], acc[nt][2], acc[nt][3]);
            *(unsigned*)(smem + (size_t)(nt*16 + row16)*68 + 16*wid + quad*4) = pw;
        }
    }
    __syncthreads();

    // ---- TP + segment-sum phase ----
    {
        unsigned mk0 = __builtin_amdgcn_readfirstlane(smaskl[0]);
        unsigned mk1 = __builtin_amdgcn_readfirstlane(smaskl[1]);
        bool iso1 = (wid < 2);
        int h = iso1 ? wid : (wid - 2);
        unsigned mkh = (h ? mk1 : mk0) & ~1u;   // first edge of half never flushes
        int ebase = 32*h;
        int dcur = sdst[ebase];

        if (iso1) {
            // o1: u = lane; fs gathered wave-coalesced from global; 3 accumulators
            const unsigned char* wp = smem + (size_t)(2*lane)*68;
            float bA = b3[2*lane], bB = b3[2*lane+1];
            float acc0 = 0.f, acc1 = 0.f, acc2 = 0.f;
            #pragma unroll
            for (int ch = 0; ch < 8; ++ch) {
                int e4 = ebase + 4*ch;
                int4 sv = *(const int4*)&ssrc[e4];
                float f0 = fs[(size_t)sv.x*64 + lane];
                float f1 = fs[(size_t)sv.y*64 + lane];
                float f2 = fs[(size_t)sv.z*64 + lane];
                float f3 = fs[(size_t)sv.w*64 + lane];
                unsigned wa4 = *(const unsigned*)(wp + e4);
                unsigned wb4 = *(const unsigned*)(wp + 68 + e4);
                float4x a00 = *(const float4x*)(&abuf[0][e4]);
                float4x a01 = *(const float4x*)(&abuf[1][e4]);
                float4x a02 = *(const float4x*)(&abuf[2][e4]);
                float4x a10 = *(const float4x*)(&abuf[3][e4]);
                float4x a11 = *(const float4x*)(&abuf[4][e4]);
                float4x a12 = *(const float4x*)(&abuf[5][e4]);
                float fv[4] = {f0, f1, f2, f3};
                float q0[4], q1[4], q2[4];
                #pragma unroll
                for (int k = 0; k < 4; ++k) {
                    float f = fv[k];
                    float wa = (e4sel(wa4, k) + bA)*f;
                    float wb = (e4sel(wb4, k) + bB)*f;
                    q0[k] = wa*a00[k] + wb*a10[k];
                    q1[k] = wa*a01[k] + wb*a11[k];
                    q2[k] = wa*a02[k] + wb*a12[k];
                }
                unsigned mch = (mkh >> (4*ch)) & 15u;
                if (mch == 0) {
                    acc0 += (q0[0] + q0[1]) + (q0[2] + q0[3]);
                    acc1 += (q1[0] + q1[1]) + (q1[2] + q1[3]);
                    acc2 += (q2[0] + q2[1]) + (q2[2] + q2[3]);
                } else {
                    #pragma unroll
                    for (int k = 0; k < 4; ++k) {
                        if (mch & (1u << k)) {
                            float* mrow = mid + (size_t)dcur*256;
                            atomicAdd(mrow + 3*lane + 0, acc0*0.125f);
                            atomicAdd(mrow + 3*lane + 1, acc1*0.125f);
                            atomicAdd(mrow + 3*lane + 2, acc2*0.125f);
                            acc0 = acc1 = acc2 = 0.f;
                            dcur = sdst[e4 + k];
                        }
                        acc0 += q0[k]; acc1 += q1[k]; acc2 += q2[k];
                    }
                }
            }
            float* mrow = mid + (size_t)dcur*256;
            atomicAdd(mrow + 3*lane + 0, acc0*0.125f);
            atomicAdd(mrow + 3*lane + 1, acc1*0.125f);
            atomicAdd(mrow + 3*lane + 2, acc2*0.125f);
        } else {
            // unified o2/o3: fvv gathered from global; per-lane row offsets + sgn/gam
            bool iso2 = lane < 16;
            int j3 = lane - 16;
            int u3 = j3 / 3;
            int m3 = j3 - 3*u3;
            int m1 = (m3 == 2) ? 0 : (m3 + 1);
            int m2 = 3 - m3 - m1;
            const unsigned char* wp;
            int rA, rB, rC;
            const float* aX0; const float* aY0; const float* aZ0;
            const float* aX1; const float* aY1; const float* aZ1;
            float bA, bB, sgn, gam, FS;
            if (iso2) {
                wp = smem + (size_t)(128 + 2*lane)*68;
                bA = b3[128 + 2*lane]; bB = b3[129 + 2*lane];
                rA = 3*lane; rB = 3*lane + 1; rC = 3*lane + 2;
                aX0 = &abuf[0][0]; aY0 = &abuf[1][0]; aZ0 = &abuf[2][0];
                aX1 = &abuf[3][0]; aY1 = &abuf[4][0]; aZ1 = &abuf[5][0];
                sgn = 1.f; gam = 1.f; FS = 0.07216878364870323f;   // 1/sqrt(192)
            } else {
                wp = smem + (size_t)(160 + 2*u3)*68;
                bA = b3[160 + 2*u3]; bB = b3[161 + 2*u3];
                rA = 3*u3 + m1; rB = 3*u3 + m2; rC = 0;            // rC dummy (gam=0)
                aX0 = &abuf[m2][0]; aY0 = &abuf[m1][0]; aZ0 = &abuf[0][0];
                aX1 = &abuf[3+m2][0]; aY1 = &abuf[3+m1][0]; aZ1 = &abuf[3][0];
                sgn = -1.f; gam = 0.f; FS = 0.08838834764831845f;  // 1/sqrt(128)
            }
            int cb = 192 + lane;
            float accb = 0.f;
            #pragma unroll
            for (int ch = 0; ch < 8; ++ch) {
                int e4 = ebase + 4*ch;
                int4 sv = *(const int4*)&ssrc[e4];
                float fa0 = fvv[(size_t)sv.x*48 + rA];
                float fb0 = fvv[(size_t)sv.x*48 + rB];
                float fc0 = fvv[(size_t)sv.x*48 + rC];
                float fa1 = fvv[(size_t)sv.y*48 + rA];
                float fb1 = fvv[(size_t)sv.y*48 + rB];
                float fc1 = fvv[(size_t)sv.y*48 + rC];
                float fa2 = fvv[(size_t)sv.z*48 + rA];
                float fb2 = fvv[(size_t)sv.z*48 + rB];
                float fc2 = fvv[(size_t)sv.z*48 + rC];
                float fa3 = fvv[(size_t)sv.w*48 + rA];
                float fb3 = fvv[(size_t)sv.w*48 + rB];
                float fc3 = fvv[(size_t)sv.w*48 + rC];
                unsigned wa4 = *(const unsigned*)(wp + e4);
                unsigned wb4 = *(const unsigned*)(wp + 68 + e4);
                float4x x0 = *(const float4x*)(aX0 + e4);
                float4x y0 = *(const float4x*)(aY0 + e4);
                float4x z0 = *(const float4x*)(aZ0 + e4);
                float4x x1 = *(const float4x*)(aX1 + e4);
                float4x y1 = *(const float4x*)(aY1 + e4);
                float4x z1 = *(const float4x*)(aZ1 + e4);
                float fav[4] = {fa0, fa1, fa2, fa3};
                float fbv[4] = {fb0, fb1, fb2, fb3};
                float fcv[4] = {fc0, fc1, fc2, fc3};
                float q[4];
                #pragma unroll
                for (int k = 0; k < 4; ++k) {
                    float fa = fav[k], fb = fbv[k], fc = fcv[k];
                    float dA = fmaf(sgn, fb*y0[k], fa*x0[k]);
                    dA = fmaf(gam, fc*z0[k], dA);
                    float dB = fmaf(sgn, fb*y1[k], fa*x1[k]);
                    dB = fmaf(gam, fc*z1[k], dB);
                    q[k] = (e4sel(wa4, k) + bA)*dA + (e4sel(wb4, k) + bB)*dB;
                }
                unsigned mch = (mkh >> (4*ch)) & 15u;
                if (mch == 0) {
                    accb += (q[0] + q[1]) + (q[2] + q[3]);
                } else {
                    #pragma unroll
                    for (int k = 0; k < 4; ++k) {
                        if (mch & (1u << k)) {
                            atomicAdd(mid + (size_t)dcur*256 + cb, accb*FS);
                            accb = 0.f;
                            dcur = sdst[e4 + k];
                        }
                        accb += q[k];
                    }
                }
            }
            atomicAdd(mid + (size_t)dcur*256 + cb, accb*FS);
        }
    }
}

// ---------------- node update + fused next-layer lin1 (type-ordered blocks, re-zeroes mid) ----------------
// Block bid processes node nsorted[bid]; consecutive blocks share a type -> their ~64KB of
// per-type weight reads hit L2 with high temporal locality (r11's LDS-batching attempt killed
// occupancy; this keeps full 10000-block parallelism).
__global__ __launch_bounds__(256) void node_update_kernel(
    const float* __restrict__ ys, const float* __restrict__ yv,
    float* __restrict__ ys_old, float* __restrict__ yv_old,
    float* __restrict__ mid,
    const int* __restrict__ types,
    const float* __restrict__ scsT, const float* __restrict__ scvT,
    const float* __restrict__ lin2sT, const float* __restrict__ lin2vT,
    const float* __restrict__ siWsT, const float* __restrict__ siWvT,
    const float* __restrict__ lin1sTn, const float* __restrict__ lin1vTn, // next layer
    const float* __restrict__ Kbuf,
    const float* __restrict__ hv, const float* __restrict__ mixv, int layer,
    float* __restrict__ fs_out, float* __restrict__ fvv_out,
    float* __restrict__ xpad, float* __restrict__ dout,
    const int* __restrict__ nsorted)
{
    int n = nsorted[blockIdx.x];
    int lane = threadIdx.x;
    __shared__ float ys_l[64], yv_l[48], mids[16], midv[240];
    __shared__ float conv_s[80], conv_v[48], sis_l[64], siv_l[48], ysn[64], yvn[48];
    int t = types[n];
    {
        float v = mid[(size_t)n*256 + lane];
        mid[(size_t)n*256 + lane] = 0.f;     // zero for next layer (replaces hipMemset)
        if (lane < 192) midv[lane] = v;
        else if (lane < 208) mids[lane-192] = v;
        else midv[192 + (lane-208)] = v;
    }
    if (lane < 64) ys_l[lane] = ys[n*64 + lane];
    else if (lane < 112) yv_l[lane-64] = yv[n*48 + (lane-64)];
    __syncthreads();
    if (lane < 80) {
        const float* Wsc = scsT + (size_t)t*5120;
        const float* W2s = lin2sT + (size_t)t*1280;
        float a_sc = 0.f, a_2 = 0.f;
        #pragma unroll
        for (int i = 0; i < 64; ++i) a_sc += ys_l[i]*Wsc[i*80 + lane];
        #pragma unroll
        for (int i = 0; i < 16; ++i) a_2 += mids[i]*W2s[i*80 + lane];
        conv_s[lane] = 0.3826834323650898f*a_sc + 0.9238795325112867f*a_2;
    } else if (lane < 144) {
        int o = lane - 80;
        float a_si = 0.f;
        #pragma unroll
        for (int i = 0; i < 64; ++i) a_si += ys_l[i]*siWsT[i*64 + o];
        sis_l[o] = a_si;
    } else if (lane < 192) {
        int j = lane - 144, o = j/3, m = j%3;
        const float* Wsc = scvT + (size_t)t*256;
        const float* W2v = lin2vT + (size_t)t*1280;
        float a_sc = 0.f, a_2 = 0.f, a_si = 0.f;
        #pragma unroll
        for (int i = 0; i < 16; ++i) {
            float y = yv_l[i*3+m];
            a_sc += y*Wsc[i*16+o];
            a_si += y*siWvT[i*16+o];
        }
        #pragma unroll
        for (int i = 0; i < 80; ++i) a_2 += midv[i*3+m]*W2v[i*16+o];
        conv_v[j] = 0.3826834323650898f*a_sc + 0.9238795325112867f*a_2;
        siv_l[j] = a_si;
    }
    __syncthreads();
    float hh = hv[layer]; float h2c = hh*hh; float mx = mixv[layer];
    if (lane < 64) {
        float cs = conv_s[lane];
        float gns = cs/(1.f + __expf(-cs));
        float ns = 2.f*ys_l[lane] - ys_old[n*64+lane] + h2c*(mx*gns + (mx-1.f)*sis_l[lane]);
        ys_old[n*64+lane] = ns;
        ysn[lane] = ns;
    } else if (lane < 112) {
        int j = lane-64, o = j/3;
        float g = 1.f/(1.f + __expf(-conv_s[64+o]));
        float gnv = g*conv_v[j];
        float nv = 2.f*yv_l[j] - yv_old[n*48+j] + h2c*(mx*gnv + (mx-1.f)*siv_l[j]);
        yv_old[n*48+j] = nv;
        yvn[j] = nv;
    }
    __syncthreads();
    if (lane < 6) {
        int i = lane/3, m = lane%3;
        float acc = 0.f;
        #pragma unroll
        for (int u = 0; u < 16; ++u) acc += Kbuf[2*u+i]*yvn[u*3+m];
        xpad[n*8 + lane] = acc;
        if (dout) dout[n*6 + lane] = acc;
    }
    // fused next-layer lin1
    if (lane < 64) {
        const float* W = lin1sTn + (size_t)t*4096;
        float acc = 0.f;
        #pragma unroll
        for (int i = 0; i < 64; ++i) acc += ysn[i]*W[i*64 + lane];
        fs_out[n*64 + lane] = acc;
    } else if (lane < 112) {
        int j = lane - 64, o = j/3, m = j%3;
        const float* W = lin1vTn + (size_t)t*256;
        float acc = 0.f;
        #pragma unroll
        for (int i = 0; i < 16; ++i) acc += yvn[i*3+m]*W[i*16 + o];
        fvv_out[n*48 + j] = acc;
    }
}

// ---------------- host ----------------
extern "C" void kernel_launch(void* const* d_in, const int* in_sizes, int n_in,
                              void* d_out, int out_size, void* d_ws, size_t ws_size,
                              hipStream_t stream)
{
    const float* x_in   = (const float*)d_in[0];
    const int*   types  = (const int*)  d_in[2];
    const int*   esrc   = (const int*)  d_in[3];
    const int*   edst   = (const int*)  d_in[4];
    const float* emb    = (const float*)d_in[5];
    const float* PU     = (const float*)d_in[6];
    const float* hv     = (const float*)d_in[7];
    const float* mixv   = (const float*)d_in[8];
    const float* si_Ws  = (const float*)d_in[9];
    const float* si_Wv  = (const float*)d_in[10];
    const float* sc_Ws  = (const float*)d_in[11];
    const float* sc_Wv  = (const float*)d_in[12];
    const float* lin1_Ws= (const float*)d_in[13];
    const float* lin1_Wv= (const float*)d_in[14];
    const float* lin2_Ws= (const float*)d_in[15];
    const float* lin2_Wv= (const float*)d_in[16];
    const float* fc_W1  = (const float*)d_in[17];
    const float* fc_b1  = (const float*)d_in[18];
    const float* fc_W2  = (const float*)d_in[19];
    const float* fc_b2  = (const float*)d_in[20];
    const float* fc_W3  = (const float*)d_in[21];
    const float* fc_b3  = (const float*)d_in[22];

    float* ws = (float*)d_ws;
    size_t off = 0;
    auto alloc = [&](size_t nf) { float* p = ws + off; off += nf; return p; };
    float* Kbuf   = alloc(64);
    float* x_pad  = alloc(80000);
    float* ys0    = alloc(640000);
    float* ys1    = alloc(640000);
    float* yv0    = alloc(480000);
    float* yv1    = alloc(480000);
    float* fsb    = alloc(640000);
    float* fvvb   = alloc(480000);
    float* midb   = alloc((size_t)NN*256);
    float* lin1sT = alloc((size_t)4*100*4096);
    float* lin1vT = alloc((size_t)4*100*256);
    float* scsT   = alloc((size_t)4*100*5120);
    float* scvT   = alloc((size_t)4*100*256);
    float* lin2sT = alloc((size_t)4*100*1280);
    float* lin2vT = alloc((size_t)4*100*1280);
    float* siWsT  = alloc((size_t)4*4096);
    float* siWvT  = alloc((size_t)4*256);
    // int region
    int* iws = (int*)(ws + off);
    size_t ioff = 0;
    auto ialloc = [&](size_t ni) { int* p = iws + ioff; ioff += ni; return p; };
    int* deg    = ialloc(NN);
    int* segoff = ialloc(NN + 8);
    int* cursor = ialloc(NN);
    int* srcs   = ialloc(NE);
    int* dsts   = ialloc(NE);
    // node-type sort region (tdeg..tcursor contiguous -> one memset)
    int* tdeg    = ialloc(104);
    int* tcursor = ialloc(104);
    int* nsorted = ialloc(NN);
    // bf16 region (16B-aligned)
    unsigned short* w1bp = (unsigned short*)(iws + ioff);   // [L][64][32]
    unsigned short* w2bp = w1bp + (size_t)4*64*32;          // [L][64][64]
    unsigned short* w3bf = w2bp + (size_t)4*64*64;          // [L][192][64]

    // K + weight prep + state init
    k_newton_kernel<<<1, 1, 0, stream>>>(PU, Kbuf);
    prep_kernel<<<(PREP_TOTAL + 255)/256, 256, 0, stream>>>(
        lin1_Ws, lin1_Wv, sc_Ws, sc_Wv, lin2_Ws, lin2_Wv, si_Ws, si_Wv,
        fc_W1, fc_W2, fc_W3, emb,
        lin1sT, lin1vT, scsT, scvT, lin2sT, lin2vT, siWsT, siWvT,
        w1bp, w2bp, w3bf);
    {
        int tot = NN*8 + NN*48 + NN*64 + NN*256;
        init_all_kernel<<<(tot + 255)/256, 256, 0, stream>>>(
            x_in, Kbuf, x_pad, yv0, yv1, ys0, ys1, fsb, midb);
    }
    init_fvv_kernel<<<(NN*48 + 255)/256, 256, 0, stream>>>(yv0, types, lin1vT, fvvb);

    // counting sort of edges by dst
    (void)hipMemsetAsync(deg, 0, NN*sizeof(int), stream);
    hist_kernel<<<(NE+255)/256, 256, 0, stream>>>(edst, deg);
    scan_kernel<<<1, 256, 0, stream>>>(deg, segoff, cursor);
    scatter_kernel<<<(NE+255)/256, 256, 0, stream>>>(esrc, edst, cursor, srcs, dsts);

    // counting sort of nodes by type (block ordering for node_update)
    (void)hipMemsetAsync(tdeg, 0, 104*sizeof(int), stream);
    thist_kernel<<<(NN+255)/256, 256, 0, stream>>>(types, tdeg);
    tscan_kernel<<<1, 128, 0, stream>>>(tdeg, tcursor);
    tscatter_kernel<<<(NN+255)/256, 256, 0, stream>>>(types, tcursor, nsorted);

    float* ys_cur = ys0; float* ys_old = ys1;
    float* yv_cur = yv0; float* yv_old = yv1;
    for (int l = 0; l < 4; ++l) {
        edge_fused_kernel<<<NE/64, 256, 0, stream>>>(
            x_pad, srcs, dsts,
            w1bp + (size_t)l*64*32,  fc_b1 + (size_t)l*64,
            w2bp + (size_t)l*64*64,  fc_b2 + (size_t)l*64,
            w3bf + (size_t)l*192*64, fc_b3 + (size_t)l*192,
            fsb, fvvb, midb);
        int ln = (l + 1) & 3;   // next-layer lin1 weights (l=3: dummy but valid)
        node_update_kernel<<<NN, 256, 0, stream>>>(
            ys_cur, yv_cur, ys_old, yv_old,
            midb, types,
            scsT   + (size_t)l*100*5120, scvT   + (size_t)l*100*256,
            lin2sT + (size_t)l*100*1280, lin2vT + (size_t)l*100*1280,
            siWsT  + (size_t)l*4096,     siWvT  + (size_t)l*256,
            lin1sT + (size_t)ln*100*4096, lin1vT + (size_t)ln*100*256,
            Kbuf, hv, mixv, l, fsb, fvvb,
            x_pad, (l == 3) ? (float*)d_out : nullptr,
            nsorted);
        float* tmp;
        tmp = ys_cur; ys_cur = ys_old; ys_old = tmp;
        tmp = yv_cur; yv_cur = yv_old; yv_old = tmp;
    }
}

// Round 14
// 938.956 us; speedup vs baseline: 2.0393x; 1.0359x over previous
//
#include <hip/hip_runtime.h>
#include <hip/hip_fp8.h>
#include <math.h>

#define NN 10000
#define NE 320000
#define PI_F 3.14159265358979323846f

typedef __attribute__((ext_vector_type(8))) short short8x;
typedef __attribute__((ext_vector_type(4))) float float4x;

#if defined(__has_builtin)
#if __has_builtin(__builtin_amdgcn_cvt_pk_fp8_f32) && __has_builtin(__builtin_amdgcn_cvt_f32_fp8)
#define HW_FP8 1
#endif
#endif

__device__ __forceinline__ unsigned short f2b(float f) {
    unsigned b = __float_as_uint(f);
    return (unsigned short)((b + 0x7FFFu + ((b >> 16) & 1u)) >> 16);
}
__device__ __forceinline__ float b2f(unsigned short u) {
    return __uint_as_float(((unsigned)u) << 16);
}
__device__ __forceinline__ float silu(float x) {
    return x / (1.f + __expf(-x));
}
__device__ __forceinline__ unsigned char f2e4(float f) {
#ifdef HW_FP8
    int r = __builtin_amdgcn_cvt_pk_fp8_f32(f, f, 0, false);
    return (unsigned char)(r & 0xff);
#else
    __hip_fp8_e4m3 q(f);
    return (unsigned char)q.__x;
#endif
}
__device__ __forceinline__ float e42f(unsigned char v) {
#ifdef HW_FP8
    return __builtin_amdgcn_cvt_f32_fp8((int)v, 0);
#else
    __hip_fp8_e4m3 q;
    q.__x = (__hip_fp8_storage_t)v;
    return (float)q;
#endif
}
// byte-select decode: builtin requires IMMEDIATE sel -> switch with literal cases
__device__ __forceinline__ float e4sel(unsigned word, int sel) {
#ifdef HW_FP8
    switch (sel & 3) {
        case 0:  return __builtin_amdgcn_cvt_f32_fp8((int)word, 0);
        case 1:  return __builtin_amdgcn_cvt_f32_fp8((int)word, 1);
        case 2:  return __builtin_amdgcn_cvt_f32_fp8((int)word, 2);
        default: return __builtin_amdgcn_cvt_f32_fp8((int)word, 3);
    }
#else
    return e42f((unsigned char)((word >> (8*(sel & 3))) & 0xffu));
#endif
}
__device__ __forceinline__ unsigned pk4(float a, float b, float c, float d) {
#ifdef HW_FP8
    unsigned w = (unsigned)__builtin_amdgcn_cvt_pk_fp8_f32(a, b, 0, false);
    w = (unsigned)__builtin_amdgcn_cvt_pk_fp8_f32(c, d, (int)w, true);
    return w;
#else
    return (unsigned)f2e4(a) | ((unsigned)f2e4(b) << 8) |
           ((unsigned)f2e4(c) << 16) | ((unsigned)f2e4(d) << 24);
#endif
}

// ---------------- K = Newton-Schulz semi-unitary (16x2) ----------------
__global__ void k_newton_kernel(const float* __restrict__ PU, float* __restrict__ Kout)
{
    if (threadIdx.x != 0 || blockIdx.x != 0) return;
    float K[32];
    float nrm = 0.f;
    for (int i = 0; i < 32; ++i) { K[i] = PU[i]; nrm += K[i]*K[i]; }
    float inv = 1.0f / sqrtf(nrm);
    for (int i = 0; i < 32; ++i) K[i] *= inv;
    for (int it = 0; it < 10; ++it) {
        float m00 = 0.f, m01 = 0.f, m11 = 0.f;
        for (int u = 0; u < 16; ++u) {
            float a = K[2*u], b = K[2*u+1];
            m00 += a*a; m01 += a*b; m11 += b*b;
        }
        for (int u = 0; u < 16; ++u) {
            float a = K[2*u], b = K[2*u+1];
            K[2*u]   = 1.5f*a - 0.5f*(a*m00 + b*m01);
            K[2*u+1] = 1.5f*b - 0.5f*(a*m01 + b*m11);
        }
    }
    for (int i = 0; i < 32; ++i) Kout[i] = K[i];
}

// ---------------- merged init: x_pad + yv init + zero ys0/ys1/fsb + zero midb ----------------
__global__ __launch_bounds__(256) void init_all_kernel(
    const float* __restrict__ x, const float* __restrict__ K,
    float* __restrict__ xp, float* __restrict__ yv0, float* __restrict__ yv1,
    float* __restrict__ ys0, float* __restrict__ ys1, float* __restrict__ fsb,
    float* __restrict__ midb)
{
    int tid = blockIdx.x*256 + threadIdx.x;
    if (tid < NN*8) {
        int n = tid >> 3, c = tid & 7;
        xp[tid] = (c < 6) ? x[n*6 + c] : 0.f;
        return;
    }
    int t2 = tid - NN*8;
    if (t2 < NN*48) {
        int n = t2/48, j = t2%48, u = j/3, m = j%3;
        float v = K[2*u]*x[n*6+m] + K[2*u+1]*x[n*6+3+m];
        yv0[t2] = v; yv1[t2] = v;
        return;
    }
    t2 -= NN*48;
    if (t2 < NN*64) { ys0[t2] = 0.f; ys1[t2] = 0.f; fsb[t2] = 0.f; return; }
    t2 -= NN*64;
    if (t2 < NN*256) midb[t2] = 0.f;
}

// ---------------- layer-0 fvv init (fs0 = 0 since ys0 = 0); lin1vT0 is bf16 ----------------
__global__ void init_fvv_kernel(const float* __restrict__ yv, const int* __restrict__ types,
                                const unsigned short* __restrict__ lin1vT0, float* __restrict__ fvv)
{
    int tid = blockIdx.x*blockDim.x + threadIdx.x;
    if (tid >= NN*48) return;
    int n = tid/48, j = tid%48, o = j/3, m = j%3;
    int t = types[n];
    const unsigned short* W = lin1vT0 + (size_t)t*256;
    float acc = 0.f;
    #pragma unroll
    for (int i = 0; i < 16; ++i) acc += yv[n*48 + i*3 + m]*b2f(W[i*16 + o]);
    fvv[tid] = acc;
}

// ---------------- per-type effective weights (device bodies: fp32-out and bf16-out) ----------------
__device__ __forceinline__ void be_body(const float* __restrict__ W, const float* __restrict__ emb,
                                        float* __restrict__ out, int id, int O, int I, float scale)
{
    int o = id % O; int r = id / O;
    int i = r % I; r /= I;
    int t = r % 100; int l = r / 100;
    const float* w  = W + (((size_t)l*O + o)*I + i)*32;
    const float* em = emb + (size_t)t*32;
    float acc = 0.f;
    #pragma unroll
    for (int e = 0; e < 32; ++e) acc += w[e]*em[e];
    out[id] = acc*scale;
}
__device__ __forceinline__ void be_body_h(const float* __restrict__ W, const float* __restrict__ emb,
                                          unsigned short* __restrict__ out, int id, int O, int I, float scale)
{
    int o = id % O; int r = id / O;
    int i = r % I; r /= I;
    int t = r % 100; int l = r / 100;
    const float* w  = W + (((size_t)l*O + o)*I + i)*32;
    const float* em = emb + (size_t)t*32;
    float acc = 0.f;
    #pragma unroll
    for (int e = 0; e < 32; ++e) acc += w[e]*em[e];
    out[id] = f2b(acc*scale);
}

// ---------------- merged weight prep (node tables emitted in bf16) ----------------
#define PREP_TOTAL (2048000 + 1638400 + 512000 + 512000 + 102400 + 102400 + 49152 + 16384 + 16384 + 8192 + 1024)
__global__ __launch_bounds__(256) void prep_kernel(
    const float* __restrict__ lin1_Ws, const float* __restrict__ lin1_Wv,
    const float* __restrict__ sc_Ws,   const float* __restrict__ sc_Wv,
    const float* __restrict__ lin2_Ws, const float* __restrict__ lin2_Wv,
    const float* __restrict__ si_Ws,   const float* __restrict__ si_Wv,
    const float* __restrict__ fc_W1,   const float* __restrict__ fc_W2,
    const float* __restrict__ fc_W3,   const float* __restrict__ emb,
    unsigned short* __restrict__ lin1sT, unsigned short* __restrict__ lin1vT,
    unsigned short* __restrict__ scsT,   unsigned short* __restrict__ scvT,
    unsigned short* __restrict__ lin2sT, unsigned short* __restrict__ lin2vT,
    float* __restrict__ siWsT,  float* __restrict__ siWvT,
    unsigned short* __restrict__ w1bp, unsigned short* __restrict__ w2bp,
    unsigned short* __restrict__ w3bf)
{
    const float s2048 = 0.022097086912079608f;   // 1/sqrt(2048)
    const float s512  = 0.044194173824159216f;   // 1/sqrt(512)
    const float s2560 = 0.019764235376052372f;   // 1/sqrt(2560)
    int tid = blockIdx.x*256 + threadIdx.x;
    if (tid < 2048000) { be_body_h(sc_Ws,   emb, scsT,   tid, 80, 64, s2048); return; }
    tid -= 2048000;
    if (tid < 1638400) { be_body_h(lin1_Ws, emb, lin1sT, tid, 64, 64, s2048); return; }
    tid -= 1638400;
    if (tid < 512000)  { be_body_h(lin2_Ws, emb, lin2sT, tid, 80, 16, s512);  return; }
    tid -= 512000;
    if (tid < 512000)  { be_body_h(lin2_Wv, emb, lin2vT, tid, 16, 80, s2560); return; }
    tid -= 512000;
    if (tid < 102400)  { be_body_h(lin1_Wv, emb, lin1vT, tid, 16, 16, s512);  return; }
    tid -= 102400;
    if (tid < 102400)  { be_body_h(sc_Wv,   emb, scvT,   tid, 16, 16, s512);  return; }
    tid -= 102400;
    if (tid < 49152) {  // w3bf = bf16(transpose(fc_W3)): [l][n=192][k=64]
        int o = tid % 64; int r = tid / 64; int i = r % 192; int l = r / 192;
        w3bf[tid] = f2b(fc_W3[((size_t)l*64 + o)*192 + i]);
        return;
    }
    tid -= 49152;
    if (tid < 16384) {  // siWsT = 0.125 * transpose(si_Ws)
        int o = tid % 64; int r = tid / 64; int i = r % 64; int l = r / 64;
        siWsT[tid] = si_Ws[((size_t)l*64 + o)*64 + i]*0.125f;
        return;
    }
    tid -= 16384;
    if (tid < 16384) {  // w2bp: pack fc_W2 K=64,N=64,KP=64
        int kk = tid % 64; int r = tid / 64; int n = r % 64; int l = r / 64;
        w2bp[tid] = f2b(fc_W2[((size_t)l*64 + kk)*64 + n]);
        return;
    }
    tid -= 16384;
    if (tid < 8192) {   // w1bp: pack fc_W1 K=16,N=64,KP=32 (zero-pad)
        int kk = tid % 32; int r = tid / 32; int n = r % 64; int l = r / 64;
        float v = (kk < 16) ? fc_W1[((size_t)l*16 + kk)*64 + n] : 0.f;
        w1bp[tid] = f2b(v);
        return;
    }
    tid -= 8192;
    if (tid < 1024) {   // siWvT = 0.25 * transpose(si_Wv)
        int o = tid % 16; int r = tid / 16; int i = r % 16; int l = r / 16;
        siWvT[tid] = si_Wv[((size_t)l*16 + o)*16 + i]*0.25f;
    }
}

// ---------------- counting sort of edges by dst ----------------
__global__ void hist_kernel(const int* __restrict__ dst, int* __restrict__ deg)
{
    int e = blockIdx.x*256 + threadIdx.x;
    if (e < NE) atomicAdd(&deg[dst[e]], 1);
}

__global__ __launch_bounds__(256) void scan_kernel(const int* __restrict__ deg,
                                                   int* __restrict__ segoff,
                                                   int* __restrict__ cursor)
{
    __shared__ int part[256];
    int tid = threadIdx.x;
    int base = tid*40;
    int s = 0;
    for (int i = 0; i < 40; ++i) { int idx = base+i; if (idx < NN) s += deg[idx]; }
    part[tid] = s;
    __syncthreads();
    for (int o = 1; o < 256; o <<= 1) {
        int v = (tid >= o) ? part[tid-o] : 0;
        __syncthreads();
        part[tid] += v;
        __syncthreads();
    }
    int excl = part[tid] - s;
    for (int i = 0; i < 40; ++i) {
        int idx = base+i;
        if (idx < NN) { segoff[idx] = excl; cursor[idx] = excl; excl += deg[idx]; }
        else if (idx == NN) { segoff[NN] = excl; }
    }
}

__global__ void scatter_kernel(const int* __restrict__ src, const int* __restrict__ dst,
                               int* __restrict__ cursor,
                               int* __restrict__ srcs, int* __restrict__ dsts)
{
    int e = blockIdx.x*256 + threadIdx.x;
    if (e >= NE) return;
    int d = dst[e];
    int p = atomicAdd(&cursor[d], 1);
    srcs[p] = src[e]; dsts[p] = d;
}

// ---------------- fused edge kernel: geometry -> MFMA MLP chain -> TP -> segment-sum -> mid ----------------
// LDS ~15 KB. __launch_bounds__(256,6): measured best (r8/r10: 133us, occ 57%);
// (256,8) measured WORSE (r9: 144us, L2 thrash at occ 72%) -- do not raise.
// mid must be zeroed before launch (init_all for layer 0; node_update re-zeroes for l+1).
__global__ __launch_bounds__(256, 6) void edge_fused_kernel(
    const float* __restrict__ xp,
    const int* __restrict__ srcs, const int* __restrict__ dsts,
    const unsigned short* __restrict__ w1b,   // [64 n][32 k] bf16 (k 16..31 zero)
    const float* __restrict__ b1,
    const unsigned short* __restrict__ w2b,   // [64 n][64 k] bf16
    const float* __restrict__ b2,
    const unsigned short* __restrict__ w3b,   // [192 n][64 k] bf16
    const float* __restrict__ b3,
    const float* __restrict__ fs, const float* __restrict__ fvv,
    float* __restrict__ mid)
{
    __shared__ __align__(16) unsigned char smem[192*68];   // wbufT comp-major; hbuf aliases front
    __shared__ float abuf[6][68];                          // [half*3+m][e]
    __shared__ int ssrc[64], sdst[64];
    __shared__ unsigned smaskl[2];
    unsigned short* hbuf = (unsigned short*)smem;          // [64][72] bf16 (9216 B)
    int lane = threadIdx.x & 63;
    int wid  = threadIdx.x >> 6;
    int eblk = blockIdx.x * 64;
    int row16 = lane & 15, quad = lane >> 4;
    int erow = 16*wid + row16;

    // stage src/dst + boundary ballot (wave 0)
    if (threadIdx.x < 64) {
        int tid = threadIdx.x;
        int own = dsts[eblk + tid];
        ssrc[tid] = srcs[eblk + tid];
        int pidx = eblk + tid - ((tid > 0) ? 1 : 0);
        int prev = dsts[pidx];
        sdst[tid] = own;
        bool nb = (tid > 0) && (own != prev);
        unsigned long long bm = __ballot(nb);
        if (tid == 0) { smaskl[0] = (unsigned)bm; smaskl[1] = (unsigned)(bm >> 32); }
    }

    // ---- phase G (lanes 0..31): geometry ----
    if (lane < 32) {
        int eidx = 16*wid + (lane & 15);
        int half = lane >> 4;
        int p = eblk + eidx;
        int s = srcs[p], d = dsts[p];
        int off = 3*half;
        const float* xs = xp + (size_t)s*8 + off;
        const float* xd = xp + (size_t)d*8 + off;
        float d0 = xs[0]-xd[0], d1 = xs[1]-xd[1], d2 = xs[2]-xd[2];
        float r = sqrtf(d0*d0 + d1*d1 + d2*d2);
        float invr = 1.0f/r;
        float u = 0.8f*r - 2.0f;
        float cut = (u > 0.f) ? 0.f : ((u < -1.f) ? 1.f : 0.5f*(1.f - __cosf(PI_F*u)));
        float sc = 1.7320508075688772f*cut*invr;
        abuf[off+0][eidx] = sc*d0;
        abuf[off+1][eidx] = sc*d1;
        abuf[off+2][eidx] = sc*d2;
        float fsc = 2.5298221281347035f*invr;
        float wr = 1.2566370614359172f*r;
        unsigned epk[4];
        #pragma unroll
        for (int k = 0; k < 4; ++k) {
            float e0 = fsc*__sinf((float)(2*k+1)*wr);
            float e1 = fsc*__sinf((float)(2*k+2)*wr);
            epk[k] = (unsigned)f2b(e0) | ((unsigned)f2b(e1) << 16);
        }
        uint4* hr = (uint4*)(hbuf + eidx*72);
        uint4 q; q.x = epk[0]; q.y = epk[1]; q.z = epk[2]; q.w = epk[3];
        hr[half] = q;
        uint4 qz; qz.x = 0; qz.y = 0; qz.z = 0; qz.w = 0;
        hr[2+half] = qz;
    }
    // hbuf rows are wave-exclusive; per-wave DS ordering suffices for GEMM1/2

    // ---- GEMM1: h1 = silu(ef @ W1 + b1), K=32 ----
    {
        short8x a = *(const short8x*)(hbuf + erow*72 + quad*8);
        float4x c[4];
        #pragma unroll
        for (int nt = 0; nt < 4; ++nt) {
            short8x b = *(const short8x*)(w1b + ((size_t)(nt*16 + row16))*32 + quad*8);
            c[nt] = __builtin_amdgcn_mfma_f32_16x16x32_bf16(a, b, (float4x){0.f,0.f,0.f,0.f}, 0, 0, 0);
        }
        #pragma unroll
        for (int nt = 0; nt < 4; ++nt) {
            float bias = b1[nt*16 + row16];
            #pragma unroll
            for (int r = 0; r < 4; ++r) {
                float h = silu(c[nt][r] + bias);
                hbuf[(16*wid + quad*4 + r)*72 + nt*16 + row16] = f2b(h);
            }
        }
    }
    // ---- GEMM2: h2 = silu(h1 @ W2 + b2), K=64 ----
    {
        short8x a0v = *(const short8x*)(hbuf + erow*72 + 0*32 + quad*8);
        short8x a1v = *(const short8x*)(hbuf + erow*72 + 1*32 + quad*8);
        float4x c[4];
        #pragma unroll
        for (int nt = 0; nt < 4; ++nt) {
            short8x b0 = *(const short8x*)(w2b + ((size_t)(nt*16 + row16))*64 + 0*32 + quad*8);
            float4x t = __builtin_amdgcn_mfma_f32_16x16x32_bf16(a0v, b0, (float4x){0.f,0.f,0.f,0.f}, 0, 0, 0);
            short8x b1v = *(const short8x*)(w2b + ((size_t)(nt*16 + row16))*64 + 1*32 + quad*8);
            c[nt] = __builtin_amdgcn_mfma_f32_16x16x32_bf16(a1v, b1v, t, 0, 0, 0);
        }
        #pragma unroll
        for (int nt = 0; nt < 4; ++nt) {
            float bias = b2[nt*16 + row16];
            #pragma unroll
            for (int r = 0; r < 4; ++r) {
                float h = silu(c[nt][r] + bias);
                hbuf[(16*wid + quad*4 + r)*72 + nt*16 + row16] = f2b(h);
            }
        }
    }
    // ---- GEMM3: w = h2 @ W3 -> fp8 comp-major into wbufT (aliases hbuf; pre-read A then barrier) ----
    {
        short8x a0v = *(const short8x*)(hbuf + erow*72 + 0*32 + quad*8);
        short8x a1v = *(const short8x*)(hbuf + erow*72 + 1*32 + quad*8);
        __syncthreads();   // all waves hold their A-fragments; hbuf region may now be overwritten
        float4x acc[12];
        #pragma unroll
        for (int nt = 0; nt < 12; ++nt) {
            short8x b0 = *(const short8x*)(w3b + ((size_t)(nt*16 + row16))*64 + 0*32 + quad*8);
            float4x t = __builtin_amdgcn_mfma_f32_16x16x32_bf16(a0v, b0, (float4x){0.f,0.f,0.f,0.f}, 0, 0, 0);
            short8x b1v = *(const short8x*)(w3b + ((size_t)(nt*16 + row16))*64 + 1*32 + quad*8);
            acc[nt] = __builtin_amdgcn_mfma_f32_16x16x32_bf16(a1v, b1v, t, 0, 0, 0);
        }
        // lane holds comp = nt*16+row16, edges e = 16*wid + quad*4 + (0..3) -> one u32 store
        #pragma unroll
        for (int nt = 0; nt < 12; ++nt) {
            unsigned pw = pk4(acc[nt][0], acc[nt][1], acc[nt][2], acc[nt][3]);
            *(unsigned*)(smem + (size_t)(nt*16 + row16)*68 + 16*wid + quad*4) = pw;
        }
    }
    __syncthreads();

    // ---- TP + segment-sum phase ----
    {
        unsigned mk0 = __builtin_amdgcn_readfirstlane(smaskl[0]);
        unsigned mk1 = __builtin_amdgcn_readfirstlane(smaskl[1]);
        bool iso1 = (wid < 2);
        int h = iso1 ? wid : (wid - 2);
        unsigned mkh = (h ? mk1 : mk0) & ~1u;   // first edge of half never flushes
        int ebase = 32*h;
        int dcur = sdst[ebase];

        if (iso1) {
            // o1: u = lane; fs gathered wave-coalesced from global; 3 accumulators
            const unsigned char* wp = smem + (size_t)(2*lane)*68;
            float bA = b3[2*lane], bB = b3[2*lane+1];
            float acc0 = 0.f, acc1 = 0.f, acc2 = 0.f;
            #pragma unroll
            for (int ch = 0; ch < 8; ++ch) {
                int e4 = ebase + 4*ch;
                int4 sv = *(const int4*)&ssrc[e4];
                float f0 = fs[(size_t)sv.x*64 + lane];
                float f1 = fs[(size_t)sv.y*64 + lane];
                float f2 = fs[(size_t)sv.z*64 + lane];
                float f3 = fs[(size_t)sv.w*64 + lane];
                unsigned wa4 = *(const unsigned*)(wp + e4);
                unsigned wb4 = *(const unsigned*)(wp + 68 + e4);
                float4x a00 = *(const float4x*)(&abuf[0][e4]);
                float4x a01 = *(const float4x*)(&abuf[1][e4]);
                float4x a02 = *(const float4x*)(&abuf[2][e4]);
                float4x a10 = *(const float4x*)(&abuf[3][e4]);
                float4x a11 = *(const float4x*)(&abuf[4][e4]);
                float4x a12 = *(const float4x*)(&abuf[5][e4]);
                float fv[4] = {f0, f1, f2, f3};
                float q0[4], q1[4], q2[4];
                #pragma unroll
                for (int k = 0; k < 4; ++k) {
                    float f = fv[k];
                    float wa = (e4sel(wa4, k) + bA)*f;
                    float wb = (e4sel(wb4, k) + bB)*f;
                    q0[k] = wa*a00[k] + wb*a10[k];
                    q1[k] = wa*a01[k] + wb*a11[k];
                    q2[k] = wa*a02[k] + wb*a12[k];
                }
                unsigned mch = (mkh >> (4*ch)) & 15u;
                if (mch == 0) {
                    acc0 += (q0[0] + q0[1]) + (q0[2] + q0[3]);
                    acc1 += (q1[0] + q1[1]) + (q1[2] + q1[3]);
                    acc2 += (q2[0] + q2[1]) + (q2[2] + q2[3]);
                } else {
                    #pragma unroll
                    for (int k = 0; k < 4; ++k) {
                        if (mch & (1u << k)) {
                            float* mrow = mid + (size_t)dcur*256;
                            atomicAdd(mrow + 3*lane + 0, acc0*0.125f);
                            atomicAdd(mrow + 3*lane + 1, acc1*0.125f);
                            atomicAdd(mrow + 3*lane + 2, acc2*0.125f);
                            acc0 = acc1 = acc2 = 0.f;
                            dcur = sdst[e4 + k];
                        }
                        acc0 += q0[k]; acc1 += q1[k]; acc2 += q2[k];
                    }
                }
            }
            float* mrow = mid + (size_t)dcur*256;
            atomicAdd(mrow + 3*lane + 0, acc0*0.125f);
            atomicAdd(mrow + 3*lane + 1, acc1*0.125f);
            atomicAdd(mrow + 3*lane + 2, acc2*0.125f);
        } else {
            // unified o2/o3: fvv gathered from global; per-lane row offsets + sgn/gam
            bool iso2 = lane < 16;
            int j3 = lane - 16;
            int u3 = j3 / 3;
            int m3 = j3 - 3*u3;
            int m1 = (m3 == 2) ? 0 : (m3 + 1);
            int m2 = 3 - m3 - m1;
            const unsigned char* wp;
            int rA, rB, rC;
            const float* aX0; const float* aY0; const float* aZ0;
            const float* aX1; const float* aY1; const float* aZ1;
            float bA, bB, sgn, gam, FS;
            if (iso2) {
                wp = smem + (size_t)(128 + 2*lane)*68;
                bA = b3[128 + 2*lane]; bB = b3[129 + 2*lane];
                rA = 3*lane; rB = 3*lane + 1; rC = 3*lane + 2;
                aX0 = &abuf[0][0]; aY0 = &abuf[1][0]; aZ0 = &abuf[2][0];
                aX1 = &abuf[3][0]; aY1 = &abuf[4][0]; aZ1 = &abuf[5][0];
                sgn = 1.f; gam = 1.f; FS = 0.07216878364870323f;   // 1/sqrt(192)
            } else {
                wp = smem + (size_t)(160 + 2*u3)*68;
                bA = b3[160 + 2*u3]; bB = b3[161 + 2*u3];
                rA = 3*u3 + m1; rB = 3*u3 + m2; rC = 0;            // rC dummy (gam=0)
                aX0 = &abuf[m2][0]; aY0 = &abuf[m1][0]; aZ0 = &abuf[0][0];
                aX1 = &abuf[3+m2][0]; aY1 = &abuf[3+m1][0]; aZ1 = &abuf[3][0];
                sgn = -1.f; gam = 0.f; FS = 0.08838834764831845f;  // 1/sqrt(128)
            }
            int cb = 192 + lane;
            float accb = 0.f;
            #pragma unroll
            for (int ch = 0; ch < 8; ++ch) {
                int e4 = ebase + 4*ch;
                int4 sv = *(const int4*)&ssrc[e4];
                float fa0 = fvv[(size_t)sv.x*48 + rA];
                float fb0 = fvv[(size_t)sv.x*48 + rB];
                float fc0 = fvv[(size_t)sv.x*48 + rC];
                float fa1 = fvv[(size_t)sv.y*48 + rA];
                float fb1 = fvv[(size_t)sv.y*48 + rB];
                float fc1 = fvv[(size_t)sv.y*48 + rC];
                float fa2 = fvv[(size_t)sv.z*48 + rA];
                float fb2 = fvv[(size_t)sv.z*48 + rB];
                float fc2 = fvv[(size_t)sv.z*48 + rC];
                float fa3 = fvv[(size_t)sv.w*48 + rA];
                float fb3 = fvv[(size_t)sv.w*48 + rB];
                float fc3 = fvv[(size_t)sv.w*48 + rC];
                unsigned wa4 = *(const unsigned*)(wp + e4);
                unsigned wb4 = *(const unsigned*)(wp + 68 + e4);
                float4x x0 = *(const float4x*)(aX0 + e4);
                float4x y0 = *(const float4x*)(aY0 + e4);
                float4x z0 = *(const float4x*)(aZ0 + e4);
                float4x x1 = *(const float4x*)(aX1 + e4);
                float4x y1 = *(const float4x*)(aY1 + e4);
                float4x z1 = *(const float4x*)(aZ1 + e4);
                float fav[4] = {fa0, fa1, fa2, fa3};
                float fbv[4] = {fb0, fb1, fb2, fb3};
                float fcv[4] = {fc0, fc1, fc2, fc3};
                float q[4];
                #pragma unroll
                for (int k = 0; k < 4; ++k) {
                    float fa = fav[k], fb = fbv[k], fc = fcv[k];
                    float dA = fmaf(sgn, fb*y0[k], fa*x0[k]);
                    dA = fmaf(gam, fc*z0[k], dA);
                    float dB = fmaf(sgn, fb*y1[k], fa*x1[k]);
                    dB = fmaf(gam, fc*z1[k], dB);
                    q[k] = (e4sel(wa4, k) + bA)*dA + (e4sel(wb4, k) + bB)*dB;
                }
                unsigned mch = (mkh >> (4*ch)) & 15u;
                if (mch == 0) {
                    accb += (q[0] + q[1]) + (q[2] + q[3]);
                } else {
                    #pragma unroll
                    for (int k = 0; k < 4; ++k) {
                        if (mch & (1u << k)) {
                            atomicAdd(mid + (size_t)dcur*256 + cb, accb*FS);
                            accb = 0.f;
                            dcur = sdst[e4 + k];
                        }
                        accb += q[k];
                    }
                }
            }
            atomicAdd(mid + (size_t)dcur*256 + cb, accb*FS);
        }
    }
}

// ---------------- node update + fused next-layer lin1 (bf16 per-type weights, re-zeroes mid) ----------------
__global__ __launch_bounds__(256) void node_update_kernel(
    const float* __restrict__ ys, const float* __restrict__ yv,
    float* __restrict__ ys_old, float* __restrict__ yv_old,
    float* __restrict__ mid,
    const int* __restrict__ types,
    const unsigned short* __restrict__ scsT, const unsigned short* __restrict__ scvT,
    const unsigned short* __restrict__ lin2sT, const unsigned short* __restrict__ lin2vT,
    const float* __restrict__ siWsT, const float* __restrict__ siWvT,
    const unsigned short* __restrict__ lin1sTn, const unsigned short* __restrict__ lin1vTn, // next layer
    const float* __restrict__ Kbuf,
    const float* __restrict__ hv, const float* __restrict__ mixv, int layer,
    float* __restrict__ fs_out, float* __restrict__ fvv_out,
    float* __restrict__ xpad, float* __restrict__ dout)
{
    int n = blockIdx.x;
    int lane = threadIdx.x;
    __shared__ float ys_l[64], yv_l[48], mids[16], midv[240];
    __shared__ float conv_s[80], conv_v[48], sis_l[64], siv_l[48], ysn[64], yvn[48];
    int t = types[n];
    {
        float v = mid[(size_t)n*256 + lane];
        mid[(size_t)n*256 + lane] = 0.f;     // zero for next layer (replaces hipMemset)
        if (lane < 192) midv[lane] = v;
        else if (lane < 208) mids[lane-192] = v;
        else midv[192 + (lane-208)] = v;
    }
    if (lane < 64) ys_l[lane] = ys[n*64 + lane];
    else if (lane < 112) yv_l[lane-64] = yv[n*48 + (lane-64)];
    __syncthreads();
    if (lane < 80) {
        const unsigned short* Wsc = scsT + (size_t)t*5120;
        const unsigned short* W2s = lin2sT + (size_t)t*1280;
        float a_sc = 0.f, a_2 = 0.f;
        #pragma unroll
        for (int i = 0; i < 64; ++i) a_sc += ys_l[i]*b2f(Wsc[i*80 + lane]);
        #pragma unroll
        for (int i = 0; i < 16; ++i) a_2 += mids[i]*b2f(W2s[i*80 + lane]);
        conv_s[lane] = 0.3826834323650898f*a_sc + 0.9238795325112867f*a_2;
    } else if (lane < 144) {
        int o = lane - 80;
        float a_si = 0.f;
        #pragma unroll
        for (int i = 0; i < 64; ++i) a_si += ys_l[i]*siWsT[i*64 + o];
        sis_l[o] = a_si;
    } else if (lane < 192) {
        int j = lane - 144, o = j/3, m = j%3;
        const unsigned short* Wsc = scvT + (size_t)t*256;
        const unsigned short* W2v = lin2vT + (size_t)t*1280;
        float a_sc = 0.f, a_2 = 0.f, a_si = 0.f;
        #pragma unroll
        for (int i = 0; i < 16; ++i) {
            float y = yv_l[i*3+m];
            a_sc += y*b2f(Wsc[i*16+o]);
            a_si += y*siWvT[i*16+o];
        }
        #pragma unroll
        for (int i = 0; i < 80; ++i) a_2 += midv[i*3+m]*b2f(W2v[i*16+o]);
        conv_v[j] = 0.3826834323650898f*a_sc + 0.9238795325112867f*a_2;
        siv_l[j] = a_si;
    }
    __syncthreads();
    float hh = hv[layer]; float h2c = hh*hh; float mx = mixv[layer];
    if (lane < 64) {
        float cs = conv_s[lane];
        float gns = cs/(1.f + __expf(-cs));
        float ns = 2.f*ys_l[lane] - ys_old[n*64+lane] + h2c*(mx*gns + (mx-1.f)*sis_l[lane]);
        ys_old[n*64+lane] = ns;
        ysn[lane] = ns;
    } else if (lane < 112) {
        int j = lane-64, o = j/3;
        float g = 1.f/(1.f + __expf(-conv_s[64+o]));
        float gnv = g*conv_v[j];
        float nv = 2.f*yv_l[j] - yv_old[n*48+j] + h2c*(mx*gnv + (mx-1.f)*siv_l[j]);
        yv_old[n*48+j] = nv;
        yvn[j] = nv;
    }
    __syncthreads();
    if (lane < 6) {
        int i = lane/3, m = lane%3;
        float acc = 0.f;
        #pragma unroll
        for (int u = 0; u < 16; ++u) acc += Kbuf[2*u+i]*yvn[u*3+m];
        xpad[n*8 + lane] = acc;
        if (dout) dout[n*6 + lane] = acc;
    }
    // fused next-layer lin1
    if (lane < 64) {
        const unsigned short* W = lin1sTn + (size_t)t*4096;
        float acc = 0.f;
        #pragma unroll
        for (int i = 0; i < 64; ++i) acc += ysn[i]*b2f(W[i*64 + lane]);
        fs_out[n*64 + lane] = acc;
    } else if (lane < 112) {
        int j = lane - 64, o = j/3, m = j%3;
        const unsigned short* W = lin1vTn + (size_t)t*256;
        float acc = 0.f;
        #pragma unroll
        for (int i = 0; i < 16; ++i) acc += yvn[i*3+m]*b2f(W[i*16 + o]);
        fvv_out[n*48 + j] = acc;
    }
}

// ---------------- host ----------------
extern "C" void kernel_launch(void* const* d_in, const int* in_sizes, int n_in,
                              void* d_out, int out_size, void* d_ws, size_t ws_size,
                              hipStream_t stream)
{
    const float* x_in   = (const float*)d_in[0];
    const int*   types  = (const int*)  d_in[2];
    const int*   esrc   = (const int*)  d_in[3];
    const int*   edst   = (const int*)  d_in[4];
    const float* emb    = (const float*)d_in[5];
    const float* PU     = (const float*)d_in[6];
    const float* hv     = (const float*)d_in[7];
    const float* mixv   = (const float*)d_in[8];
    const float* si_Ws  = (const float*)d_in[9];
    const float* si_Wv  = (const float*)d_in[10];
    const float* sc_Ws  = (const float*)d_in[11];
    const float* sc_Wv  = (const float*)d_in[12];
    const float* lin1_Ws= (const float*)d_in[13];
    const float* lin1_Wv= (const float*)d_in[14];
    const float* lin2_Ws= (const float*)d_in[15];
    const float* lin2_Wv= (const float*)d_in[16];
    const float* fc_W1  = (const float*)d_in[17];
    const float* fc_b1  = (const float*)d_in[18];
    const float* fc_W2  = (const float*)d_in[19];
    const float* fc_b2  = (const float*)d_in[20];
    const float* fc_W3  = (const float*)d_in[21];
    const float* fc_b3  = (const float*)d_in[22];

    float* ws = (float*)d_ws;
    size_t off = 0;
    auto alloc = [&](size_t nf) { float* p = ws + off; off += nf; return p; };
    float* Kbuf   = alloc(64);
    float* x_pad  = alloc(80000);
    float* ys0    = alloc(640000);
    float* ys1    = alloc(640000);
    float* yv0    = alloc(480000);
    float* yv1    = alloc(480000);
    float* fsb    = alloc(640000);
    float* fvvb   = alloc(480000);
    float* midb   = alloc((size_t)NN*256);
    float* siWsT  = alloc((size_t)4*4096);
    float* siWvT  = alloc((size_t)4*256);
    // int region
    int* iws = (int*)(ws + off);
    size_t ioff = 0;
    auto ialloc = [&](size_t ni) { int* p = iws + ioff; ioff += ni; return p; };
    int* deg    = ialloc(NN);
    int* segoff = ialloc(NN + 8);
    int* cursor = ialloc(NN);
    int* srcs   = ialloc(NE);
    int* dsts   = ialloc(NE);
    // bf16 region (16B-aligned)
    unsigned short* hw = (unsigned short*)(iws + ioff);
    size_t hoff = 0;
    auto halloc = [&](size_t nh) { unsigned short* p = hw + hoff; hoff += nh; return p; };
    unsigned short* w1bp   = halloc((size_t)4*64*32);     // [L][64][32]
    unsigned short* w2bp   = halloc((size_t)4*64*64);     // [L][64][64]
    unsigned short* w3bf   = halloc((size_t)4*192*64);    // [L][192][64]
    unsigned short* lin1sT = halloc((size_t)4*100*4096);
    unsigned short* lin1vT = halloc((size_t)4*100*256);
    unsigned short* scsT   = halloc((size_t)4*100*5120);
    unsigned short* scvT   = halloc((size_t)4*100*256);
    unsigned short* lin2sT = halloc((size_t)4*100*1280);
    unsigned short* lin2vT = halloc((size_t)4*100*1280);

    // K + weight prep + state init
    k_newton_kernel<<<1, 1, 0, stream>>>(PU, Kbuf);
    prep_kernel<<<(PREP_TOTAL + 255)/256, 256, 0, stream>>>(
        lin1_Ws, lin1_Wv, sc_Ws, sc_Wv, lin2_Ws, lin2_Wv, si_Ws, si_Wv,
        fc_W1, fc_W2, fc_W3, emb,
        lin1sT, lin1vT, scsT, scvT, lin2sT, lin2vT, siWsT, siWvT,
        w1bp, w2bp, w3bf);
    {
        int tot = NN*8 + NN*48 + NN*64 + NN*256;
        init_all_kernel<<<(tot + 255)/256, 256, 0, stream>>>(
            x_in, Kbuf, x_pad, yv0, yv1, ys0, ys1, fsb, midb);
    }
    init_fvv_kernel<<<(NN*48 + 255)/256, 256, 0, stream>>>(yv0, types, lin1vT, fvvb);

    // counting sort of edges by dst
    (void)hipMemsetAsync(deg, 0, NN*sizeof(int), stream);
    hist_kernel<<<(NE+255)/256, 256, 0, stream>>>(edst, deg);
    scan_kernel<<<1, 256, 0, stream>>>(deg, segoff, cursor);
    scatter_kernel<<<(NE+255)/256, 256, 0, stream>>>(esrc, edst, cursor, srcs, dsts);

    float* ys_cur = ys0; float* ys_old = ys1;
    float* yv_cur = yv0; float* yv_old = yv1;
    for (int l = 0; l < 4; ++l) {
        edge_fused_kernel<<<NE/64, 256, 0, stream>>>(
            x_pad, srcs, dsts,
            w1bp + (size_t)l*64*32,  fc_b1 + (size_t)l*64,
            w2bp + (size_t)l*64*64,  fc_b2 + (size_t)l*64,
            w3bf + (size_t)l*192*64, fc_b3 + (size_t)l*192,
            fsb, fvvb, midb);
        int ln = (l + 1) & 3;   // next-layer lin1 weights (l=3: dummy but valid)
        node_update_kernel<<<NN, 256, 0, stream>>>(
            ys_cur, yv_cur, ys_old, yv_old,
            midb, types,
            scsT   + (size_t)l*100*5120, scvT   + (size_t)l*100*256,
            lin2sT + (size_t)l*100*1280, lin2vT + (size_t)l*100*1280,
            siWsT  + (size_t)l*4096,     siWvT  + (size_t)l*256,
            lin1sT + (size_t)ln*100*4096, lin1vT + (size_t)ln*100*256,
            Kbuf, hv, mixv, l, fsb, fvvb,
            x_pad, (l == 3) ? (float*)d_out : nullptr);
        float* tmp;
        tmp = ys_cur; ys_cur = ys_old; ys_old = tmp;
        tmp = yv_cur; yv_cur = yv_old; yv_old = tmp;
    }
}